// Round 4
// baseline (917.654 us; speedup 1.0000x reference)
//
#include <hip/hip_runtime.h>
#include <hip/hip_bf16.h>
#include <cstdint>

#define TN 8192
#define DN 1024
#define HN 4096
#define EN 8
#define PADMAX 18432  // 72*256: 16384 pairs + 8*255 worst-case pad, rounded to 256

typedef __attribute__((ext_vector_type(8))) short short8;
typedef __attribute__((ext_vector_type(4))) float f32x4;
typedef __attribute__((ext_vector_type(4))) unsigned short ushort4v;

__device__ inline unsigned short f2bf(float f) {
  unsigned u = __builtin_bit_cast(unsigned, f);
  u = u + 0x7fffu + ((u >> 16) & 1u);
  return (unsigned short)(u >> 16);
}

__device__ inline float gelu_f(float v) {
  float z = 0.7978845608028654f * (v + 0.044715f * v * v * v);
  float ez = __expf(2.f * z);
  float th = 1.f - 2.f / (ez + 1.f);
  return 0.5f * v * (1.f + th);
}

__device__ inline void gload_lds16(const void* g, void* l) {
  __builtin_amdgcn_global_load_lds(
      (const __attribute__((address_space(1))) unsigned int*)g,
      (__attribute__((address_space(3))) unsigned int*)l, 16, 0, 0);
}

__global__ __launch_bounds__(256) void cvt_bf16_k(const float* __restrict__ src,
                                                  unsigned short* __restrict__ dst,
                                                  long n4) {
  long i = (long)blockIdx.x * blockDim.x + threadIdx.x;
  long stride = (long)gridDim.x * blockDim.x;
  for (; i < n4; i += stride) {
    float4 v = ((const float4*)src)[i];
    ushort4v o;
    o.x = f2bf(v.x); o.y = f2bf(v.y); o.z = f2bf(v.z); o.w = f2bf(v.w);
    ((ushort4v*)dst)[i] = o;
  }
}

__global__ __launch_bounds__(256) void router_k(const float* __restrict__ x,
                                                const float* __restrict__ rw,
                                                int* __restrict__ eids,
                                                float* __restrict__ wts,
                                                int* __restrict__ cnt) {
  int wid = threadIdx.x >> 6, lane = threadIdx.x & 63;
  int t = blockIdx.x * 4 + wid;
  const float* xr = x + (long)t * DN;
  float a[EN];
#pragma unroll
  for (int e = 0; e < EN; ++e) a[e] = 0.f;
  for (int k = lane; k < DN; k += 64) {
    float xv = xr[k];
#pragma unroll
    for (int e = 0; e < EN; ++e) a[e] += xv * rw[e * DN + k];
  }
#pragma unroll
  for (int off = 32; off > 0; off >>= 1) {
#pragma unroll
    for (int e = 0; e < EN; ++e) a[e] += __shfl_xor(a[e], off);
  }
  if (lane == 0) {
    float mx = a[0];
#pragma unroll
    for (int e = 1; e < EN; ++e) mx = fmaxf(mx, a[e]);
    float p[EN], s = 0.f;
#pragma unroll
    for (int e = 0; e < EN; ++e) { p[e] = __expf(a[e] - mx); s += p[e]; }
    int e0 = 0; float b0 = p[0];
#pragma unroll
    for (int e = 1; e < EN; ++e) if (p[e] > b0) { b0 = p[e]; e0 = e; }
    int e1 = -1; float b1 = -1.f;
#pragma unroll
    for (int e = 0; e < EN; ++e) if (e != e0 && p[e] > b1) { b1 = p[e]; e1 = e; }
    float inv = 1.f / s;
    eids[2 * t] = e0; eids[2 * t + 1] = e1;
    wts[2 * t] = b0 * inv; wts[2 * t + 1] = b1 * inv;
    atomicAdd(&cnt[e0], 1);
    atomicAdd(&cnt[e1], 1);
  }
}

__global__ void offsets_k(const int* __restrict__ cnt, int* __restrict__ poff) {
  if (threadIdx.x == 0 && blockIdx.x == 0) {
    int o = 0;
    for (int e = 0; e < EN; ++e) { poff[e] = o; o += (cnt[e] + 255) & ~255; }
    poff[EN] = o;
  }
}

__global__ __launch_bounds__(256) void scatter_k(const int* __restrict__ eids,
                                                 const float* __restrict__ wts,
                                                 const int* __restrict__ poff,
                                                 int* __restrict__ cursor,
                                                 int* __restrict__ pairTok,
                                                 float* __restrict__ pairW) {
  int t = blockIdx.x * 256 + threadIdx.x;
#pragma unroll
  for (int k = 0; k < 2; ++k) {
    int e = eids[2 * t + k];
    int p = atomicAdd(&cursor[e], 1);
    int pos = poff[e] + p;
    pairTok[pos] = t;
    pairW[pos] = wts[2 * t + k];
  }
}

// ---- 256x256 4-phase-per-K-tile GEMM (T1+T2+T3+T4+T5) ----
// R4 change: NO sched_barrier(0) anywhere (m141 trap); raw s_barrier bracketed by
// zero-cost compile-time memory fences; pinned lgkmcnt(0) after opening barriers
// keeps the cross-wave stage-vs-read ordering safe. Compiler free-schedules
// VALU/MFMA/addr-calc across the phase bodies.

#define BAR() { asm volatile("" ::: "memory"); __builtin_amdgcn_s_barrier(); \
                asm volatile("" ::: "memory"); }
#define LGKM0() { asm volatile("s_waitcnt lgkmcnt(0)" ::: "memory"); }

#define LDA_H(QM, PAR) { const char* _b = smem + (PAR)*32768 + waveM*16384;          \
  _Pragma("unroll") for (int m = 0; m < 4; ++m) {                                    \
    int row = ((QM)*4 + m)*16 + (lane & 15); int cb = row * 128;                     \
    a[m][0] = *(const short8*)(_b + cb + (((lane>>4) ^ (row&7)) * 16));              \
    a[m][1] = *(const short8*)(_b + cb + (((4 + (lane>>4)) ^ (row&7)) * 16)); } }

#define LDB_H(NH, PAR) { const char* _b = smem + 65536 + (PAR)*32768 + (waveN>>1)*16384; \
  _Pragma("unroll") for (int n = 0; n < 2; ++n) {                                    \
    int row = (waveN&1)*64 + ((NH)*2+n)*16 + (lane & 15); int cb = row * 128;        \
    b[(NH)*2+n][0] = *(const short8*)(_b + cb + (((lane>>4) ^ (row&7)) * 16));       \
    b[(NH)*2+n][1] = *(const short8*)(_b + cb + (((4 + (lane>>4)) ^ (row&7)) * 16)); } }

#define MM16(QM, NH) { __builtin_amdgcn_s_setprio(1);                                \
  _Pragma("unroll") for (int m = 0; m < 4; ++m)                                      \
    _Pragma("unroll") for (int n = 0; n < 2; ++n) {                                  \
      acc[(QM)*4+m][(NH)*2+n] = __builtin_amdgcn_mfma_f32_16x16x32_bf16(             \
          a[m][0], b[(NH)*2+n][0], acc[(QM)*4+m][(NH)*2+n], 0, 0, 0);                \
      acc[(QM)*4+m][(NH)*2+n] = __builtin_amdgcn_mfma_f32_16x16x32_bf16(             \
          a[m][1], b[(NH)*2+n][1], acc[(QM)*4+m][(NH)*2+n], 0, 0, 0); }              \
  __builtin_amdgcn_s_setprio(0); }

template <int MODE, bool BBF16>
__global__ __launch_bounds__(512, 2) void moe_gemm256_k(
    const unsigned short* __restrict__ Ab, const void* __restrict__ Bsrc,
    void* __restrict__ OutP, const int* __restrict__ pairTok,
    const float* __restrict__ pairW, const int* __restrict__ poff, int chunkStart) {
  constexpr int KD = (MODE == 1) ? DN : HN;
  constexpr int ND = (MODE == 1) ? HN : DN;
  constexpr int SPLIT = (MODE == 1) ? 1 : 4;
  constexpr int KLEN = KD / SPLIT;
  constexpr int NT = KLEN / 64;

  extern __shared__ char smem[];

  // T1: bijective XCD swizzle over (x,y)
  int NX = gridDim.x;
  int NXY = NX * gridDim.y;
  int orig = blockIdx.y * NX + blockIdx.x;
  int qq = NXY >> 3, rrm = NXY & 7;
  int xcd = orig & 7, pos = orig >> 3;
  int wg = (xcd < rrm ? xcd * (qq + 1) : rrm * (qq + 1) + (xcd - rrm) * qq) + pos;
  int tileN = (wg % NX) * 256;
  int tileStart = chunkStart + (wg / NX) * 256;

  int Ppad = poff[EN];
  if (tileStart >= Ppad) return;
  int e = 0;
  while (e < EN - 1 && tileStart >= poff[e + 1]) ++e;

  int tid = threadIdx.x;
  int wid = tid >> 6, lane = tid & 63;
  int waveM = wid >> 2, waveN = wid & 3;
  int kbase = blockIdx.z * KLEN;

  // staging sources: load j covers q = j*512+tid -> row q>>3, linear slot q&7,
  // global slot s = (q&7)^(row&7)  (inverse swizzle so LDS linear dest works)
  int r0 = tid >> 3, s0 = (tid & 7) ^ (r0 & 7);
  const char* aSrc[2][2];
  const char* bSrc[2][2];
#pragma unroll
  for (int h = 0; h < 2; ++h) {
    int rh0 = h * 128 + r0, rh1 = h * 128 + 64 + r0;
    long ar0, ar1;
    if (MODE == 1) {
      int t0 = pairTok[tileStart + rh0]; if (t0 < 0) t0 = 0;
      int t1 = pairTok[tileStart + rh1]; if (t1 < 0) t1 = 0;
      ar0 = (long)t0 * KD; ar1 = (long)t1 * KD;
    } else {
      ar0 = (long)(tileStart - chunkStart + rh0) * KD;
      ar1 = (long)(tileStart - chunkStart + rh1) * KD;
    }
    aSrc[h][0] = (const char*)(Ab + ar0 + kbase + s0 * 8);
    aSrc[h][1] = (const char*)(Ab + ar1 + kbase + s0 * 8);
    long bb0 = (long)e * ND * KD + (long)(tileN + rh0) * KD + kbase + s0 * 8;
    long bb1 = (long)e * ND * KD + (long)(tileN + rh1) * KD + kbase + s0 * 8;
    bSrc[h][0] = (const char*)Bsrc + bb0 * (BBF16 ? 2 : 4);
    bSrc[h][1] = (const char*)Bsrc + bb1 * (BBF16 ? 2 : 4);
  }

  auto stageA = [&](int k0, int dstPar, int h) {
    char* d = smem + dstPar * 32768 + h * 16384 + wid * 1024;
    gload_lds16(aSrc[h][0] + (long)k0 * 2, d);
    gload_lds16(aSrc[h][1] + (long)k0 * 2, d + 8192);
  };
  auto stageB = [&](int k0, int dstPar, int h) {
    if constexpr (BBF16) {
      char* d = smem + 65536 + dstPar * 32768 + h * 16384 + wid * 1024;
      gload_lds16(bSrc[h][0] + (long)k0 * 2, d);
      gload_lds16(bSrc[h][1] + (long)k0 * 2, d + 8192);
    } else {
      char* d = smem + 65536 + dstPar * 32768 + h * 16384 + tid * 16;
#pragma unroll
      for (int j = 0; j < 2; ++j) {
        const float4* pf = (const float4*)(bSrc[h][j] + (long)k0 * 4);
        float4 v0 = pf[0], v1 = pf[1];
        short8 pk;
        pk[0] = (short)f2bf(v0.x); pk[1] = (short)f2bf(v0.y);
        pk[2] = (short)f2bf(v0.z); pk[3] = (short)f2bf(v0.w);
        pk[4] = (short)f2bf(v1.x); pk[5] = (short)f2bf(v1.y);
        pk[6] = (short)f2bf(v1.z); pk[7] = (short)f2bf(v1.w);
        *(short8*)(d + j * 8192) = pk;
      }
    }
  };

  f32x4 acc[8][4];
#pragma unroll
  for (int m = 0; m < 8; ++m)
#pragma unroll
    for (int n = 0; n < 4; ++n) acc[m][n] = (f32x4){0.f, 0.f, 0.f, 0.f};
  short8 a[4][2], b[4][2];

  // prologue: tile0 {A0,A1,B0,B1} -> buf0, tile1 {B0,B1} -> buf1.
  stageA(0, 0, 0); stageA(0, 0, 1);
  stageB(0, 0, 0); stageB(0, 0, 1);
  stageB(64, 1, 0); stageB(64, 1, 1);
  if constexpr (BBF16) {
    asm volatile("s_waitcnt vmcnt(4)" ::: "memory");
  } else {
    asm volatile("s_waitcnt vmcnt(0) lgkmcnt(0)" ::: "memory");
  }
  BAR();

  for (int t = 0; t < NT; ++t) {
    int P = t & 1;
    int k1 = (t + 1) * 64, k2 = (t + 2) * 64;
    // ph1: Q(M0,N0)
    LDA_H(0, P); LDB_H(0, P);
    if (t + 1 < NT) stageA(k1, P ^ 1, 0);
    BAR(); LGKM0();
    MM16(0, 0);
    BAR();
    // ph2: Q(M0,N1)
    LDB_H(1, P);
    if (t + 1 < NT) stageA(k1, P ^ 1, 1);
    BAR(); LGKM0();
    MM16(0, 1);
    BAR();
    // ph3: Q(M1,N0)
    LDA_H(1, P);
    if (t + 2 < NT) stageB(k2, P, 0);
    BAR(); LGKM0();
    MM16(1, 0);
    BAR();
    // ph4: Q(M1,N1)
    if (t + 2 < NT) stageB(k2, P, 1);
    BAR();
    MM16(1, 1);
    if (BBF16 && t + 2 < NT) {
      asm volatile("s_waitcnt vmcnt(4)" ::: "memory");
    } else {
      asm volatile("s_waitcnt vmcnt(0)" ::: "memory");
    }
    BAR();
  }

  if (MODE == 1) {
    unsigned short* hbp = (unsigned short*)OutP;
    int rl0 = tileStart - chunkStart + waveM * 128;
#pragma unroll
    for (int m = 0; m < 8; ++m) {
#pragma unroll
      for (int r = 0; r < 4; ++r) {
        int rl = rl0 + m * 16 + (lane >> 4) * 4 + r;
#pragma unroll
        for (int n = 0; n < 4; ++n) {
          int col = tileN + waveN * 64 + n * 16 + (lane & 15);
          hbp[(long)rl * HN + col] = f2bf(gelu_f(acc[m][n][r]));
        }
      }
    }
  } else {
    float* outF = (float*)OutP;
#pragma unroll
    for (int m = 0; m < 8; ++m) {
#pragma unroll
      for (int r = 0; r < 4; ++r) {
        int p = tileStart + waveM * 128 + m * 16 + (lane >> 4) * 4 + r;
        int tok = pairTok[p];
        if (tok < 0) continue;
        float wv = pairW[p];
#pragma unroll
        for (int n = 0; n < 4; ++n) {
          int col = tileN + waveN * 64 + n * 16 + (lane & 15);
          atomicAdd(&outF[(long)tok * DN + col], wv * acc[m][n][r]);
        }
      }
    }
  }
}

extern "C" void kernel_launch(void* const* d_in, const int* in_sizes, int n_in,
                              void* d_out, int out_size, void* d_ws, size_t ws_size,
                              hipStream_t stream) {
  const float* x = (const float*)d_in[0];
  const float* rw = (const float*)d_in[1];
  const float* w1 = (const float*)d_in[2];
  const float* w2 = (const float*)d_in[3];
  char* W = (char*)d_ws;
  size_t off = 0;
  auto alloc = [&](size_t sz) {
    off = (off + 255) & ~(size_t)255;
    size_t r = off; off += sz; return r;
  };
  size_t ctrlO = alloc(256);  // cnt[8], cursor[8], poff[9]
  size_t eidsO = alloc((size_t)TN * 2 * 4);
  size_t wtsO  = alloc((size_t)TN * 2 * 4);
  size_t ptokO = alloc((size_t)PADMAX * 4);
  size_t pwO   = alloc((size_t)PADMAX * 4);
  size_t xbO   = alloc((size_t)TN * DN * 2);
  size_t wB = (size_t)EN * HN * DN * 2;
  size_t afterFixed = (off + 255) & ~(size_t)255;
  bool bw = ws_size >= afterFixed + 2 * wB + (size_t)256 * HN * 2 + 4096;
  size_t w1bO = 0, w2bO = 0;
  if (bw) { w1bO = alloc(wB); w2bO = alloc(wB); }
  size_t hbase = (off + 255) & ~(size_t)255;
  size_t avail = ws_size > hbase ? ws_size - hbase : (size_t)256 * HN * 2;
  long Cl = (long)(avail / ((size_t)HN * 2));
  if (Cl > PADMAX) Cl = PADMAX;
  Cl &= ~255l;
  if (Cl < 256) Cl = 256;
  int C = (int)Cl;
  size_t hbO = alloc((size_t)C * HN * 2);
  int nCh = (PADMAX + C - 1) / C;

  int* cnt = (int*)(W + ctrlO);
  int* cursor = cnt + 8;
  int* poff = cnt + 16;
  int* eids = (int*)(W + eidsO);
  float* wts = (float*)(W + wtsO);
  int* pairTok = (int*)(W + ptokO);
  float* pairW = (float*)(W + pwO);
  unsigned short* xb = (unsigned short*)(W + xbO);
  unsigned short* hb = (unsigned short*)(W + hbO);

  hipFuncSetAttribute(reinterpret_cast<const void*>(moe_gemm256_k<1, true>),
                      hipFuncAttributeMaxDynamicSharedMemorySize, 131072);
  hipFuncSetAttribute(reinterpret_cast<const void*>(moe_gemm256_k<2, true>),
                      hipFuncAttributeMaxDynamicSharedMemorySize, 131072);
  hipFuncSetAttribute(reinterpret_cast<const void*>(moe_gemm256_k<1, false>),
                      hipFuncAttributeMaxDynamicSharedMemorySize, 131072);
  hipFuncSetAttribute(reinterpret_cast<const void*>(moe_gemm256_k<2, false>),
                      hipFuncAttributeMaxDynamicSharedMemorySize, 131072);

  hipMemsetAsync(W + ctrlO, 0, 256, stream);
  hipMemsetAsync(W + ptokO, 0xFF, (size_t)PADMAX * 4, stream);  // pairTok = -1
  hipMemsetAsync(d_out, 0, (size_t)TN * DN * 4, stream);

  cvt_bf16_k<<<1024, 256, 0, stream>>>(x, xb, (long)TN * DN / 4);
  if (bw) {
    cvt_bf16_k<<<2048, 256, 0, stream>>>(w1, (unsigned short*)(W + w1bO), (long)EN * HN * DN / 4);
    cvt_bf16_k<<<2048, 256, 0, stream>>>(w2, (unsigned short*)(W + w2bO), (long)EN * HN * DN / 4);
  }
  router_k<<<TN / 4, 256, 0, stream>>>(x, rw, eids, wts, cnt);
  offsets_k<<<1, 1, 0, stream>>>(cnt, poff);
  scatter_k<<<TN / 256, 256, 0, stream>>>(eids, wts, poff, cursor, pairTok, pairW);

  int Ctiles = C / 256;
  for (int c = 0; c < nCh; ++c) {
    int cs = c * C;
    if (bw) {
      moe_gemm256_k<1, true><<<dim3(HN / 256, Ctiles, 1), 512, 131072, stream>>>(
          xb, W + w1bO, hb, pairTok, pairW, poff, cs);
      moe_gemm256_k<2, true><<<dim3(DN / 256, Ctiles, 4), 512, 131072, stream>>>(
          hb, W + w2bO, d_out, pairTok, pairW, poff, cs);
    } else {
      moe_gemm256_k<1, false><<<dim3(HN / 256, Ctiles, 1), 512, 131072, stream>>>(
          xb, w1, hb, pairTok, pairW, poff, cs);
      moe_gemm256_k<2, false><<<dim3(DN / 256, Ctiles, 4), 512, 131072, stream>>>(
          hb, w2, d_out, pairTok, pairW, poff, cs);
    }
  }
}

// Round 5
// 786.419 us; speedup vs baseline: 1.1669x; 1.1669x over previous
//
#include <hip/hip_runtime.h>
#include <hip/hip_bf16.h>
#include <cstdint>

#define TN 8192
#define DN 1024
#define HN 4096
#define EN 8
#define PADMAX 18432  // 72*256: 16384 pairs + 8*255 worst-case pad, rounded to 256

typedef __attribute__((ext_vector_type(8))) short short8;
typedef __attribute__((ext_vector_type(4))) float f32x4;
typedef __attribute__((ext_vector_type(4))) unsigned short ushort4v;

__device__ inline unsigned short f2bf(float f) {
  unsigned u = __builtin_bit_cast(unsigned, f);
  u = u + 0x7fffu + ((u >> 16) & 1u);
  return (unsigned short)(u >> 16);
}
__device__ inline float bf2f(unsigned short u) {
  unsigned v = ((unsigned)u) << 16;
  return __builtin_bit_cast(float, v);
}

__device__ inline float gelu_f(float v) {
  float z = 0.7978845608028654f * (v + 0.044715f * v * v * v);
  float ez = __expf(2.f * z);
  float th = 1.f - 2.f / (ez + 1.f);
  return 0.5f * v * (1.f + th);
}

__device__ inline void gload_lds16(const void* g, void* l) {
  __builtin_amdgcn_global_load_lds(
      (const __attribute__((address_space(1))) unsigned int*)g,
      (__attribute__((address_space(3))) unsigned int*)l, 16, 0, 0);
}

__global__ __launch_bounds__(256) void cvt_bf16_k(const float* __restrict__ src,
                                                  unsigned short* __restrict__ dst,
                                                  long n4) {
  long i = (long)blockIdx.x * blockDim.x + threadIdx.x;
  long stride = (long)gridDim.x * blockDim.x;
  for (; i < n4; i += stride) {
    float4 v = ((const float4*)src)[i];
    ushort4v o;
    o.x = f2bf(v.x); o.y = f2bf(v.y); o.z = f2bf(v.z); o.w = f2bf(v.w);
    ((ushort4v*)dst)[i] = o;
  }
}

__global__ __launch_bounds__(256) void router_k(const float* __restrict__ x,
                                                const float* __restrict__ rw,
                                                int* __restrict__ eids,
                                                float* __restrict__ wts,
                                                int* __restrict__ cnt) {
  int wid = threadIdx.x >> 6, lane = threadIdx.x & 63;
  int t = blockIdx.x * 4 + wid;
  const float* xr = x + (long)t * DN;
  float a[EN];
#pragma unroll
  for (int e = 0; e < EN; ++e) a[e] = 0.f;
  for (int k = lane; k < DN; k += 64) {
    float xv = xr[k];
#pragma unroll
    for (int e = 0; e < EN; ++e) a[e] += xv * rw[e * DN + k];
  }
#pragma unroll
  for (int off = 32; off > 0; off >>= 1) {
#pragma unroll
    for (int e = 0; e < EN; ++e) a[e] += __shfl_xor(a[e], off);
  }
  if (lane == 0) {
    float mx = a[0];
#pragma unroll
    for (int e = 1; e < EN; ++e) mx = fmaxf(mx, a[e]);
    float p[EN], s = 0.f;
#pragma unroll
    for (int e = 0; e < EN; ++e) { p[e] = __expf(a[e] - mx); s += p[e]; }
    int e0 = 0; float b0 = p[0];
#pragma unroll
    for (int e = 1; e < EN; ++e) if (p[e] > b0) { b0 = p[e]; e0 = e; }
    int e1 = -1; float b1 = -1.f;
#pragma unroll
    for (int e = 0; e < EN; ++e) if (e != e0 && p[e] > b1) { b1 = p[e]; e1 = e; }
    float inv = 1.f / s;
    eids[2 * t] = e0; eids[2 * t + 1] = e1;
    wts[2 * t] = b0 * inv; wts[2 * t + 1] = b1 * inv;
    atomicAdd(&cnt[e0], 1);
    atomicAdd(&cnt[e1], 1);
  }
}

__global__ void offsets_k(const int* __restrict__ cnt, int* __restrict__ poff) {
  if (threadIdx.x == 0 && blockIdx.x == 0) {
    int o = 0;
    for (int e = 0; e < EN; ++e) { poff[e] = o; o += (cnt[e] + 255) & ~255; }
    poff[EN] = o;
  }
}

__global__ __launch_bounds__(256) void scatter_k(const int* __restrict__ eids,
                                                 const float* __restrict__ wts,
                                                 const int* __restrict__ poff,
                                                 int* __restrict__ cursor,
                                                 int* __restrict__ pairTok,
                                                 float* __restrict__ pairW,
                                                 int* __restrict__ slotPos) {
  int t = blockIdx.x * 256 + threadIdx.x;
#pragma unroll
  for (int k = 0; k < 2; ++k) {
    int e = eids[2 * t + k];
    int p = atomicAdd(&cursor[e], 1);
    int pos = poff[e] + p;
    pairTok[pos] = t;
    pairW[pos] = wts[2 * t + k];
    slotPos[2 * t + k] = pos;
  }
}

// out[t] = w0 * yb[pos0] + w1 * yb[pos1]   (one block per token, 4 f32/thread)
__global__ __launch_bounds__(256) void combine_k(const unsigned short* __restrict__ yb,
                                                 const float* __restrict__ wts,
                                                 const int* __restrict__ slotPos,
                                                 float* __restrict__ out) {
  int t = blockIdx.x;
  int p0 = slotPos[2 * t], p1 = slotPos[2 * t + 1];
  float w0 = wts[2 * t], w1 = wts[2 * t + 1];
  int c = threadIdx.x * 4;
  ushort4v y0 = *(const ushort4v*)(yb + (long)p0 * DN + c);
  ushort4v y1 = *(const ushort4v*)(yb + (long)p1 * DN + c);
  float4 o;
  o.x = w0 * bf2f(y0.x) + w1 * bf2f(y1.x);
  o.y = w0 * bf2f(y0.y) + w1 * bf2f(y1.y);
  o.z = w0 * bf2f(y0.z) + w1 * bf2f(y1.z);
  o.w = w0 * bf2f(y0.w) + w1 * bf2f(y1.w);
  *(float4*)(out + (long)t * DN + c) = o;
}

// ---- 256x256 4-phase-per-K-tile GEMM ----
// MODE 1: h = gelu(x_gathered @ w1[e]^T)  K=1024, N=4096 -> hb bf16
// MODE 2: yb[pos] = h @ w2[e]^T           K=4096, N=1024 -> dense bf16 per pair
// MODE 3: fallback: out += w * (h @ w2^T) via fp32 atomics (split-K gridDim.z)

#define BAR() { asm volatile("" ::: "memory"); __builtin_amdgcn_s_barrier(); \
                asm volatile("" ::: "memory"); }
#define LGKM0() { asm volatile("s_waitcnt lgkmcnt(0)" ::: "memory"); }

#define LDA_H(QM, PAR) { const char* _b = smem + (PAR)*32768 + waveM*16384;          \
  _Pragma("unroll") for (int m = 0; m < 4; ++m) {                                    \
    int row = ((QM)*4 + m)*16 + (lane & 15); int cb = row * 128;                     \
    a[m][0] = *(const short8*)(_b + cb + (((lane>>4) ^ (row&7)) * 16));              \
    a[m][1] = *(const short8*)(_b + cb + (((4 + (lane>>4)) ^ (row&7)) * 16)); } }

#define LDB_H(NH, PAR) { const char* _b = smem + 65536 + (PAR)*32768 + (waveN>>1)*16384; \
  _Pragma("unroll") for (int n = 0; n < 2; ++n) {                                    \
    int row = (waveN&1)*64 + ((NH)*2+n)*16 + (lane & 15); int cb = row * 128;        \
    b[(NH)*2+n][0] = *(const short8*)(_b + cb + (((lane>>4) ^ (row&7)) * 16));       \
    b[(NH)*2+n][1] = *(const short8*)(_b + cb + (((4 + (lane>>4)) ^ (row&7)) * 16)); } }

#define MM16(QM, NH) { __builtin_amdgcn_s_setprio(1);                                \
  _Pragma("unroll") for (int m = 0; m < 4; ++m)                                      \
    _Pragma("unroll") for (int n = 0; n < 2; ++n) {                                  \
      acc[(QM)*4+m][(NH)*2+n] = __builtin_amdgcn_mfma_f32_16x16x32_bf16(             \
          a[m][0], b[(NH)*2+n][0], acc[(QM)*4+m][(NH)*2+n], 0, 0, 0);                \
      acc[(QM)*4+m][(NH)*2+n] = __builtin_amdgcn_mfma_f32_16x16x32_bf16(             \
          a[m][1], b[(NH)*2+n][1], acc[(QM)*4+m][(NH)*2+n], 0, 0, 0); }              \
  __builtin_amdgcn_s_setprio(0); }

template <int MODE, bool BBF16>
__global__ __launch_bounds__(512, 2) void moe_gemm256_k(
    const unsigned short* __restrict__ Ab, const void* __restrict__ Bsrc,
    void* __restrict__ OutP, const int* __restrict__ pairTok,
    const float* __restrict__ pairW, const int* __restrict__ poff, int chunkStart) {
  constexpr int KD = (MODE == 1) ? DN : HN;
  constexpr int ND = (MODE == 1) ? HN : DN;
  constexpr int SPLIT = (MODE == 3) ? 2 : 1;
  constexpr int KLEN = KD / SPLIT;
  constexpr int NT = KLEN / 64;

  extern __shared__ char smem[];

  // T1: bijective XCD swizzle over (x,y)
  int NX = gridDim.x;
  int NXY = NX * gridDim.y;
  int orig = blockIdx.y * NX + blockIdx.x;
  int qq = NXY >> 3, rrm = NXY & 7;
  int xcd = orig & 7, pos = orig >> 3;
  int wg = (xcd < rrm ? xcd * (qq + 1) : rrm * (qq + 1) + (xcd - rrm) * qq) + pos;
  int tileN = (wg % NX) * 256;
  int tileStart = chunkStart + (wg / NX) * 256;

  int Ppad = poff[EN];
  if (tileStart >= Ppad) return;
  int e = 0;
  while (e < EN - 1 && tileStart >= poff[e + 1]) ++e;

  int tid = threadIdx.x;
  int wid = tid >> 6, lane = tid & 63;
  int waveM = wid >> 2, waveN = wid & 3;
  int kbase = (MODE == 3) ? blockIdx.z * KLEN : 0;

  // staging sources: load j covers q = j*512+tid -> row q>>3, linear slot q&7,
  // global slot s = (q&7)^(row&7)  (inverse swizzle so LDS linear dest works)
  int r0 = tid >> 3, s0 = (tid & 7) ^ (r0 & 7);
  const char* aSrc[2][2];
  const char* bSrc[2][2];
#pragma unroll
  for (int h = 0; h < 2; ++h) {
    int rh0 = h * 128 + r0, rh1 = h * 128 + 64 + r0;
    long ar0, ar1;
    if (MODE == 1) {
      int t0 = pairTok[tileStart + rh0]; if (t0 < 0) t0 = 0;
      int t1 = pairTok[tileStart + rh1]; if (t1 < 0) t1 = 0;
      ar0 = (long)t0 * KD; ar1 = (long)t1 * KD;
    } else {
      ar0 = (long)(tileStart - chunkStart + rh0) * KD;
      ar1 = (long)(tileStart - chunkStart + rh1) * KD;
    }
    aSrc[h][0] = (const char*)(Ab + ar0 + kbase + s0 * 8);
    aSrc[h][1] = (const char*)(Ab + ar1 + kbase + s0 * 8);
    long bb0 = (long)e * ND * KD + (long)(tileN + rh0) * KD + kbase + s0 * 8;
    long bb1 = (long)e * ND * KD + (long)(tileN + rh1) * KD + kbase + s0 * 8;
    bSrc[h][0] = (const char*)Bsrc + bb0 * (BBF16 ? 2 : 4);
    bSrc[h][1] = (const char*)Bsrc + bb1 * (BBF16 ? 2 : 4);
  }

  auto stageA = [&](int k0, int dstPar, int h) {
    char* d = smem + dstPar * 32768 + h * 16384 + wid * 1024;
    gload_lds16(aSrc[h][0] + (long)k0 * 2, d);
    gload_lds16(aSrc[h][1] + (long)k0 * 2, d + 8192);
  };
  auto stageB = [&](int k0, int dstPar, int h) {
    if constexpr (BBF16) {
      char* d = smem + 65536 + dstPar * 32768 + h * 16384 + wid * 1024;
      gload_lds16(bSrc[h][0] + (long)k0 * 2, d);
      gload_lds16(bSrc[h][1] + (long)k0 * 2, d + 8192);
    } else {
      char* d = smem + 65536 + dstPar * 32768 + h * 16384 + tid * 16;
#pragma unroll
      for (int j = 0; j < 2; ++j) {
        const float4* pf = (const float4*)(bSrc[h][j] + (long)k0 * 4);
        float4 v0 = pf[0], v1 = pf[1];
        short8 pk;
        pk[0] = (short)f2bf(v0.x); pk[1] = (short)f2bf(v0.y);
        pk[2] = (short)f2bf(v0.z); pk[3] = (short)f2bf(v0.w);
        pk[4] = (short)f2bf(v1.x); pk[5] = (short)f2bf(v1.y);
        pk[6] = (short)f2bf(v1.z); pk[7] = (short)f2bf(v1.w);
        *(short8*)(d + j * 8192) = pk;
      }
    }
  };

  f32x4 acc[8][4];
#pragma unroll
  for (int m = 0; m < 8; ++m)
#pragma unroll
    for (int n = 0; n < 4; ++n) acc[m][n] = (f32x4){0.f, 0.f, 0.f, 0.f};
  short8 a[4][2], b[4][2];

  // prologue: tile0 {A0,A1,B0,B1} -> buf0, tile1 {B0,B1} -> buf1.
  stageA(0, 0, 0); stageA(0, 0, 1);
  stageB(0, 0, 0); stageB(0, 0, 1);
  stageB(64, 1, 0); stageB(64, 1, 1);
  if constexpr (BBF16) {
    asm volatile("s_waitcnt vmcnt(4)" ::: "memory");
  } else {
    asm volatile("s_waitcnt vmcnt(0) lgkmcnt(0)" ::: "memory");
  }
  BAR();

  for (int t = 0; t < NT; ++t) {
    int P = t & 1;
    int k1 = (t + 1) * 64, k2 = (t + 2) * 64;
    // ph1: Q(M0,N0)
    LDA_H(0, P); LDB_H(0, P);
    if (t + 1 < NT) stageA(k1, P ^ 1, 0);
    BAR(); LGKM0();
    MM16(0, 0);
    BAR();
    // ph2: Q(M0,N1)
    LDB_H(1, P);
    if (t + 1 < NT) stageA(k1, P ^ 1, 1);
    BAR(); LGKM0();
    MM16(0, 1);
    BAR();
    // ph3: Q(M1,N0)
    LDA_H(1, P);
    if (t + 2 < NT) stageB(k2, P, 0);
    BAR(); LGKM0();
    MM16(1, 0);
    BAR();
    // ph4: Q(M1,N1)
    if (t + 2 < NT) stageB(k2, P, 1);
    BAR();
    MM16(1, 1);
    if (BBF16 && t + 2 < NT) {
      asm volatile("s_waitcnt vmcnt(4)" ::: "memory");
    } else {
      asm volatile("s_waitcnt vmcnt(0)" ::: "memory");
    }
    BAR();
  }

  if (MODE == 1) {
    unsigned short* hbp = (unsigned short*)OutP;
    int rl0 = tileStart - chunkStart + waveM * 128;
#pragma unroll
    for (int m = 0; m < 8; ++m) {
#pragma unroll
      for (int r = 0; r < 4; ++r) {
        int rl = rl0 + m * 16 + (lane >> 4) * 4 + r;
#pragma unroll
        for (int n = 0; n < 4; ++n) {
          int col = tileN + waveN * 64 + n * 16 + (lane & 15);
          hbp[(long)rl * HN + col] = f2bf(gelu_f(acc[m][n][r]));
        }
      }
    }
  } else if (MODE == 2) {
    // dense per-pair bf16 output; pad rows write garbage that is never read
    unsigned short* ybp = (unsigned short*)OutP;
#pragma unroll
    for (int m = 0; m < 8; ++m) {
#pragma unroll
      for (int r = 0; r < 4; ++r) {
        int p = tileStart + waveM * 128 + m * 16 + (lane >> 4) * 4 + r;
#pragma unroll
        for (int n = 0; n < 4; ++n) {
          int col = tileN + waveN * 64 + n * 16 + (lane & 15);
          ybp[(long)p * ND + col] = f2bf(acc[m][n][r]);
        }
      }
    }
  } else {
    float* outF = (float*)OutP;
#pragma unroll
    for (int m = 0; m < 8; ++m) {
#pragma unroll
      for (int r = 0; r < 4; ++r) {
        int p = tileStart + waveM * 128 + m * 16 + (lane >> 4) * 4 + r;
        int tok = pairTok[p];
        if (tok < 0) continue;
        float wv = pairW[p];
#pragma unroll
        for (int n = 0; n < 4; ++n) {
          int col = tileN + waveN * 64 + n * 16 + (lane & 15);
          atomicAdd(&outF[(long)tok * DN + col], wv * acc[m][n][r]);
        }
      }
    }
  }
}

extern "C" void kernel_launch(void* const* d_in, const int* in_sizes, int n_in,
                              void* d_out, int out_size, void* d_ws, size_t ws_size,
                              hipStream_t stream) {
  const float* x = (const float*)d_in[0];
  const float* rw = (const float*)d_in[1];
  const float* w1 = (const float*)d_in[2];
  const float* w2 = (const float*)d_in[3];
  char* W = (char*)d_ws;
  size_t off = 0;
  auto alloc = [&](size_t sz) {
    off = (off + 255) & ~(size_t)255;
    size_t r = off; off += sz; return r;
  };
  size_t ctrlO = alloc(256);  // cnt[8], cursor[8], poff[9]
  size_t eidsO = alloc((size_t)TN * 2 * 4);
  size_t wtsO  = alloc((size_t)TN * 2 * 4);
  size_t ptokO = alloc((size_t)PADMAX * 4);
  size_t pwO   = alloc((size_t)PADMAX * 4);
  size_t sposO = alloc((size_t)TN * 2 * 4);
  size_t xbO   = alloc((size_t)TN * DN * 2);
  size_t wB = (size_t)EN * HN * DN * 2;
  size_t afterFixed = (off + 255) & ~(size_t)255;
  bool bw = ws_size >= afterFixed + 2 * wB + (size_t)256 * HN * 2 + 4096;
  size_t w1bO = 0, w2bO = 0;
  if (bw) { w1bO = alloc(wB); w2bO = alloc(wB); }
  size_t ybB = (size_t)PADMAX * DN * 2;
  size_t afterW = (off + 255) & ~(size_t)255;
  bool dense = ws_size >= afterW + ybB + (size_t)256 * HN * 2 + 4096;
  size_t ybO = 0;
  if (dense) ybO = alloc(ybB);
  size_t hbase = (off + 255) & ~(size_t)255;
  size_t avail = ws_size > hbase ? ws_size - hbase : (size_t)256 * HN * 2;
  long Cl = (long)(avail / ((size_t)HN * 2));
  if (Cl > PADMAX) Cl = PADMAX;
  Cl &= ~255l;
  if (Cl < 256) Cl = 256;
  int C = (int)Cl;
  size_t hbO = alloc((size_t)C * HN * 2);
  int nCh = (PADMAX + C - 1) / C;

  int* cnt = (int*)(W + ctrlO);
  int* cursor = cnt + 8;
  int* poff = cnt + 16;
  int* eids = (int*)(W + eidsO);
  float* wts = (float*)(W + wtsO);
  int* pairTok = (int*)(W + ptokO);
  float* pairW = (float*)(W + pwO);
  int* slotPos = (int*)(W + sposO);
  unsigned short* xb = (unsigned short*)(W + xbO);
  unsigned short* hb = (unsigned short*)(W + hbO);
  unsigned short* yb = (unsigned short*)(W + ybO);

  hipFuncSetAttribute(reinterpret_cast<const void*>(moe_gemm256_k<1, true>),
                      hipFuncAttributeMaxDynamicSharedMemorySize, 131072);
  hipFuncSetAttribute(reinterpret_cast<const void*>(moe_gemm256_k<2, true>),
                      hipFuncAttributeMaxDynamicSharedMemorySize, 131072);
  hipFuncSetAttribute(reinterpret_cast<const void*>(moe_gemm256_k<3, true>),
                      hipFuncAttributeMaxDynamicSharedMemorySize, 131072);
  hipFuncSetAttribute(reinterpret_cast<const void*>(moe_gemm256_k<1, false>),
                      hipFuncAttributeMaxDynamicSharedMemorySize, 131072);
  hipFuncSetAttribute(reinterpret_cast<const void*>(moe_gemm256_k<2, false>),
                      hipFuncAttributeMaxDynamicSharedMemorySize, 131072);
  hipFuncSetAttribute(reinterpret_cast<const void*>(moe_gemm256_k<3, false>),
                      hipFuncAttributeMaxDynamicSharedMemorySize, 131072);

  hipMemsetAsync(W + ctrlO, 0, 256, stream);
  hipMemsetAsync(W + ptokO, 0xFF, (size_t)PADMAX * 4, stream);  // pairTok = -1
  if (!dense) hipMemsetAsync(d_out, 0, (size_t)TN * DN * 4, stream);

  cvt_bf16_k<<<1024, 256, 0, stream>>>(x, xb, (long)TN * DN / 4);
  if (bw) {
    cvt_bf16_k<<<2048, 256, 0, stream>>>(w1, (unsigned short*)(W + w1bO), (long)EN * HN * DN / 4);
    cvt_bf16_k<<<2048, 256, 0, stream>>>(w2, (unsigned short*)(W + w2bO), (long)EN * HN * DN / 4);
  }
  router_k<<<TN / 4, 256, 0, stream>>>(x, rw, eids, wts, cnt);
  offsets_k<<<1, 1, 0, stream>>>(cnt, poff);
  scatter_k<<<TN / 256, 256, 0, stream>>>(eids, wts, poff, cursor, pairTok, pairW, slotPos);

  int Ctiles = C / 256;
  for (int c = 0; c < nCh; ++c) {
    int cs = c * C;
    if (bw) {
      moe_gemm256_k<1, true><<<dim3(HN / 256, Ctiles, 1), 512, 131072, stream>>>(
          xb, W + w1bO, hb, pairTok, pairW, poff, cs);
      if (dense) {
        moe_gemm256_k<2, true><<<dim3(DN / 256, Ctiles, 1), 512, 131072, stream>>>(
            hb, W + w2bO, yb, pairTok, pairW, poff, cs);
      } else {
        moe_gemm256_k<3, true><<<dim3(DN / 256, Ctiles, 2), 512, 131072, stream>>>(
            hb, W + w2bO, d_out, pairTok, pairW, poff, cs);
      }
    } else {
      moe_gemm256_k<1, false><<<dim3(HN / 256, Ctiles, 1), 512, 131072, stream>>>(
          xb, w1, hb, pairTok, pairW, poff, cs);
      if (dense) {
        moe_gemm256_k<2, false><<<dim3(DN / 256, Ctiles, 1), 512, 131072, stream>>>(
            hb, w2, yb, pairTok, pairW, poff, cs);
      } else {
        moe_gemm256_k<3, false><<<dim3(DN / 256, Ctiles, 2), 512, 131072, stream>>>(
            hb, w2, d_out, pairTok, pairW, poff, cs);
      }
    }
  }
  if (dense) {
    combine_k<<<TN, 256, 0, stream>>>(yb, wts, slotPos, (float*)d_out);
  }
}

// Round 6
// 785.604 us; speedup vs baseline: 1.1681x; 1.0010x over previous
//
#include <hip/hip_runtime.h>
#include <hip/hip_bf16.h>
#include <cstdint>

#define TN 8192
#define DN 1024
#define HN 4096
#define EN 8
#define PADMAX 18432  // 72*256: 16384 pairs + 8*255 worst-case pad, rounded to 256

typedef __attribute__((ext_vector_type(8))) short short8;
typedef __attribute__((ext_vector_type(4))) float f32x4;
typedef __attribute__((ext_vector_type(4))) unsigned short ushort4v;

__device__ inline unsigned short f2bf(float f) {
  unsigned u = __builtin_bit_cast(unsigned, f);
  u = u + 0x7fffu + ((u >> 16) & 1u);
  return (unsigned short)(u >> 16);
}
__device__ inline float bf2f(unsigned short u) {
  unsigned v = ((unsigned)u) << 16;
  return __builtin_bit_cast(float, v);
}

__device__ inline float gelu_f(float v) {
  float z = 0.7978845608028654f * (v + 0.044715f * v * v * v);
  float ez = __expf(2.f * z);
  float th = 1.f - 2.f / (ez + 1.f);
  return 0.5f * v * (1.f + th);
}

__device__ inline void gload_lds16(const void* g, void* l) {
  __builtin_amdgcn_global_load_lds(
      (const __attribute__((address_space(1))) unsigned int*)g,
      (__attribute__((address_space(3))) unsigned int*)l, 16, 0, 0);
}

__global__ __launch_bounds__(256) void cvt_bf16_k(const float* __restrict__ src,
                                                  unsigned short* __restrict__ dst,
                                                  long n4) {
  long i = (long)blockIdx.x * blockDim.x + threadIdx.x;
  long stride = (long)gridDim.x * blockDim.x;
  for (; i < n4; i += stride) {
    float4 v = ((const float4*)src)[i];
    ushort4v o;
    o.x = f2bf(v.x); o.y = f2bf(v.y); o.z = f2bf(v.z); o.w = f2bf(v.w);
    ((ushort4v*)dst)[i] = o;
  }
}

__global__ __launch_bounds__(256) void router_k(const float* __restrict__ x,
                                                const float* __restrict__ rw,
                                                int* __restrict__ eids,
                                                float* __restrict__ wts,
                                                int* __restrict__ cnt) {
  int wid = threadIdx.x >> 6, lane = threadIdx.x & 63;
  int t = blockIdx.x * 4 + wid;
  const float* xr = x + (long)t * DN;
  float a[EN];
#pragma unroll
  for (int e = 0; e < EN; ++e) a[e] = 0.f;
  for (int k = lane; k < DN; k += 64) {
    float xv = xr[k];
#pragma unroll
    for (int e = 0; e < EN; ++e) a[e] += xv * rw[e * DN + k];
  }
#pragma unroll
  for (int off = 32; off > 0; off >>= 1) {
#pragma unroll
    for (int e = 0; e < EN; ++e) a[e] += __shfl_xor(a[e], off);
  }
  if (lane == 0) {
    float mx = a[0];
#pragma unroll
    for (int e = 1; e < EN; ++e) mx = fmaxf(mx, a[e]);
    float p[EN], s = 0.f;
#pragma unroll
    for (int e = 0; e < EN; ++e) { p[e] = __expf(a[e] - mx); s += p[e]; }
    int e0 = 0; float b0 = p[0];
#pragma unroll
    for (int e = 1; e < EN; ++e) if (p[e] > b0) { b0 = p[e]; e0 = e; }
    int e1 = -1; float b1 = -1.f;
#pragma unroll
    for (int e = 0; e < EN; ++e) if (e != e0 && p[e] > b1) { b1 = p[e]; e1 = e; }
    float inv = 1.f / s;
    eids[2 * t] = e0; eids[2 * t + 1] = e1;
    wts[2 * t] = b0 * inv; wts[2 * t + 1] = b1 * inv;
    atomicAdd(&cnt[e0], 1);
    atomicAdd(&cnt[e1], 1);
  }
}

__global__ void offsets_k(const int* __restrict__ cnt, int* __restrict__ poff) {
  if (threadIdx.x == 0 && blockIdx.x == 0) {
    int o = 0;
    for (int e = 0; e < EN; ++e) { poff[e] = o; o += (cnt[e] + 255) & ~255; }
    poff[EN] = o;
  }
}

__global__ __launch_bounds__(256) void scatter_k(const int* __restrict__ eids,
                                                 const float* __restrict__ wts,
                                                 const int* __restrict__ poff,
                                                 int* __restrict__ cursor,
                                                 int* __restrict__ pairTok,
                                                 float* __restrict__ pairW,
                                                 int* __restrict__ slotPos) {
  int t = blockIdx.x * 256 + threadIdx.x;
#pragma unroll
  for (int k = 0; k < 2; ++k) {
    int e = eids[2 * t + k];
    int p = atomicAdd(&cursor[e], 1);
    int pos = poff[e] + p;
    pairTok[pos] = t;
    pairW[pos] = wts[2 * t + k];
    slotPos[2 * t + k] = pos;
  }
}

// xg[pos] = xb[pairTok[pos]] : make fc1's A operand linear (4 rows/block, 2 passes)
__global__ __launch_bounds__(256) void gather_k(const unsigned short* __restrict__ xb,
                                                const int* __restrict__ pairTok,
                                                unsigned short* __restrict__ xg) {
  int p = blockIdx.x * 4 + (threadIdx.x >> 6);
  int lane = threadIdx.x & 63;
  int tok = pairTok[p];
  if (tok < 0) tok = 0;
  const short8* src = (const short8*)(xb + (long)tok * DN);
  short8* dst = (short8*)(xg + (long)p * DN);
  dst[lane] = src[lane];
  dst[64 + lane] = src[64 + lane];
}

// out[t] = w0 * yb[pos0] + w1 * yb[pos1]
__global__ __launch_bounds__(256) void combine_k(const unsigned short* __restrict__ yb,
                                                 const float* __restrict__ wts,
                                                 const int* __restrict__ slotPos,
                                                 float* __restrict__ out) {
  int t = blockIdx.x;
  int p0 = slotPos[2 * t], p1 = slotPos[2 * t + 1];
  float w0 = wts[2 * t], w1 = wts[2 * t + 1];
  int c = threadIdx.x * 4;
  ushort4v y0 = *(const ushort4v*)(yb + (long)p0 * DN + c);
  ushort4v y1 = *(const ushort4v*)(yb + (long)p1 * DN + c);
  float4 o;
  o.x = w0 * bf2f(y0.x) + w1 * bf2f(y1.x);
  o.y = w0 * bf2f(y0.y) + w1 * bf2f(y1.y);
  o.z = w0 * bf2f(y0.z) + w1 * bf2f(y1.z);
  o.w = w0 * bf2f(y0.w) + w1 * bf2f(y1.w);
  *(float4*)(out + (long)t * DN + c) = o;
}

// ---- 128x128 GEMM, BK=64, 4 waves (2x2), 64 KiB LDS dbuf -> 2 blocks/CU ----
// MODE 1: h = gelu(xg @ w1[e]^T)   A linear (pre-gathered), K=1024, N=4096
// MODE 2: yb = h @ w2[e]^T         A linear (chunk-local),  K=4096, N=1024
// MODE 3: fallback atomics with split-K 2
// LDS: A[par] at par*16384, B[par] at 32768+par*16384 (16 KB each).
// Per K-tile t: ph1 {LDA 8 + LDB01 4 reads} BAR lgkm0 MM16 BAR;
//               ph2 {LDB23 4 reads; stageA(t+2,par)} BAR lgkm0 MM16;
//               tail {stageB(t+2,par); vmcnt(8)} BAR.
// vmcnt(8): A(t+2),B(t+2) (8 newest loads) stay in flight; A/B(t+1) drained.

#define BAR() { asm volatile("" ::: "memory"); __builtin_amdgcn_s_barrier(); \
                asm volatile("" ::: "memory"); }
#define LGKM0() { asm volatile("s_waitcnt lgkmcnt(0)" ::: "memory"); }

#define LDA4(PAR) { const char* _b = smem + (PAR)*16384;                             \
  _Pragma("unroll") for (int m = 0; m < 4; ++m) {                                    \
    int row = waveM*64 + m*16 + (lane & 15); int cb = row * 128;                     \
    a[m][0] = *(const short8*)(_b + cb + (((lane>>4) ^ (row&7)) * 16));              \
    a[m][1] = *(const short8*)(_b + cb + (((4 + (lane>>4)) ^ (row&7)) * 16)); } }

#define LDB2(NH, PAR) { const char* _b = smem + 32768 + (PAR)*16384;                 \
  _Pragma("unroll") for (int n = 0; n < 2; ++n) {                                    \
    int row = waveN*64 + ((NH)*2+n)*16 + (lane & 15); int cb = row * 128;            \
    b[(NH)*2+n][0] = *(const short8*)(_b + cb + (((lane>>4) ^ (row&7)) * 16));       \
    b[(NH)*2+n][1] = *(const short8*)(_b + cb + (((4 + (lane>>4)) ^ (row&7)) * 16)); } }

#define MM16(NH) { __builtin_amdgcn_s_setprio(1);                                    \
  _Pragma("unroll") for (int m = 0; m < 4; ++m)                                      \
    _Pragma("unroll") for (int n = 0; n < 2; ++n) {                                  \
      acc[m][(NH)*2+n] = __builtin_amdgcn_mfma_f32_16x16x32_bf16(                    \
          a[m][0], b[(NH)*2+n][0], acc[m][(NH)*2+n], 0, 0, 0);                       \
      acc[m][(NH)*2+n] = __builtin_amdgcn_mfma_f32_16x16x32_bf16(                    \
          a[m][1], b[(NH)*2+n][1], acc[m][(NH)*2+n], 0, 0, 0); }                     \
  __builtin_amdgcn_s_setprio(0); }

template <int MODE, bool BBF16>
__global__ __launch_bounds__(256, 2) void moe_gemm128_k(
    const unsigned short* __restrict__ Ab, const void* __restrict__ Bsrc,
    void* __restrict__ OutP, const int* __restrict__ pairTok,
    const float* __restrict__ pairW, const int* __restrict__ poff, int chunkStart) {
  constexpr int KD = (MODE == 1) ? DN : HN;
  constexpr int ND = (MODE == 1) ? HN : DN;
  constexpr int SPLIT = (MODE == 3) ? 2 : 1;
  constexpr int KLEN = KD / SPLIT;
  constexpr int NT = KLEN / 64;

  extern __shared__ char smem[];

  // T1: bijective XCD swizzle over (x,y)
  int NX = gridDim.x;
  int NXY = NX * gridDim.y;
  int orig = blockIdx.y * NX + blockIdx.x;
  int qq = NXY >> 3, rrm = NXY & 7;
  int xcd = orig & 7, pos = orig >> 3;
  int wg = (xcd < rrm ? xcd * (qq + 1) : rrm * (qq + 1) + (xcd - rrm) * qq) + pos;
  int tileN = (wg % NX) * 128;
  int tileStart = chunkStart + (wg / NX) * 128;

  int Ppad = poff[EN];
  if (tileStart >= Ppad) return;
  int e = 0;
  while (e < EN - 1 && tileStart >= poff[e + 1]) ++e;

  int tid = threadIdx.x;
  int wid = tid >> 6, lane = tid & 63;
  int waveM = wid >> 1, waveN = wid & 1;
  int kbase = (MODE == 3) ? blockIdx.z * KLEN : 0;

  // staging sources: chunk j covers q = j*256+tid -> row q>>3, linear slot q&7,
  // global slot s = (q&7)^(row&7) (inverse swizzle; LDS dest stays linear)
  int r0 = tid >> 3;
  const char* aSrc[4];
  const char* bSrc[4];
#pragma unroll
  for (int j = 0; j < 4; ++j) {
    int row = j * 32 + r0;
    int s = (tid & 7) ^ (row & 7);
    long abase = (MODE == 1) ? (long)(tileStart + row) * KD
                             : (long)(tileStart - chunkStart + row) * KD;
    aSrc[j] = (const char*)(Ab + abase + kbase + s * 8);
    long bb = (long)e * ND * KD + (long)(tileN + row) * KD + kbase + s * 8;
    bSrc[j] = (const char*)Bsrc + bb * (BBF16 ? 2 : 4);
  }

  auto stageA = [&](int k0, int par) {
#pragma unroll
    for (int j = 0; j < 4; ++j)
      gload_lds16(aSrc[j] + (long)k0 * 2, smem + par * 16384 + (j * 256 + tid) * 16);
  };
  auto stageB = [&](int k0, int par) {
    if constexpr (BBF16) {
#pragma unroll
      for (int j = 0; j < 4; ++j)
        gload_lds16(bSrc[j] + (long)k0 * 2, smem + 32768 + par * 16384 + (j * 256 + tid) * 16);
    } else {
#pragma unroll
      for (int j = 0; j < 4; ++j) {
        const float4* pf = (const float4*)(bSrc[j] + (long)k0 * 4);
        float4 v0 = pf[0], v1 = pf[1];
        short8 pk;
        pk[0] = (short)f2bf(v0.x); pk[1] = (short)f2bf(v0.y);
        pk[2] = (short)f2bf(v0.z); pk[3] = (short)f2bf(v0.w);
        pk[4] = (short)f2bf(v1.x); pk[5] = (short)f2bf(v1.y);
        pk[6] = (short)f2bf(v1.z); pk[7] = (short)f2bf(v1.w);
        *(short8*)(smem + 32768 + par * 16384 + (j * 256 + tid) * 16) = pk;
      }
    }
  };

  f32x4 acc[4][4];
#pragma unroll
  for (int m = 0; m < 4; ++m)
#pragma unroll
    for (int n = 0; n < 4; ++n) acc[m][n] = (f32x4){0.f, 0.f, 0.f, 0.f};
  short8 a[4][2], b[4][2];

  // prologue: tile0 -> buf0, tile1 -> buf1 (16 loads); keep tile1's 8 in flight
  stageA(0, 0); stageB(0, 0);
  stageA(64, 1); stageB(64, 1);
  if constexpr (BBF16) {
    asm volatile("s_waitcnt vmcnt(8)" ::: "memory");
  } else {
    asm volatile("s_waitcnt vmcnt(0) lgkmcnt(0)" ::: "memory");
  }
  BAR();

  for (int t = 0; t < NT; ++t) {
    int P = t & 1;
    int k2 = (t + 2) * 64;
    // ph1
    LDA4(P); LDB2(0, P);
    BAR(); LGKM0();
    MM16(0);
    BAR();
    // ph2 (A[P] reads all done -> safe to overwrite A[P] with tile t+2)
    LDB2(1, P);
    if (t + 2 < NT) stageA(k2, P);
    BAR(); LGKM0();
    MM16(1);
    // tail (B[P] reads done -> stage B(t+2))
    if (t + 2 < NT) stageB(k2, P);
    if (BBF16 && t + 2 < NT) {
      asm volatile("s_waitcnt vmcnt(8)" ::: "memory");
    } else {
      asm volatile("s_waitcnt vmcnt(0)" ::: "memory");
    }
    BAR();
  }

  if (MODE == 1) {
    unsigned short* hbp = (unsigned short*)OutP;
    int rl0 = tileStart - chunkStart + waveM * 64;
#pragma unroll
    for (int m = 0; m < 4; ++m) {
#pragma unroll
      for (int r = 0; r < 4; ++r) {
        int rl = rl0 + m * 16 + (lane >> 4) * 4 + r;
#pragma unroll
        for (int n = 0; n < 4; ++n) {
          int col = tileN + waveN * 64 + n * 16 + (lane & 15);
          hbp[(long)rl * HN + col] = f2bf(gelu_f(acc[m][n][r]));
        }
      }
    }
  } else if (MODE == 2) {
    unsigned short* ybp = (unsigned short*)OutP;
#pragma unroll
    for (int m = 0; m < 4; ++m) {
#pragma unroll
      for (int r = 0; r < 4; ++r) {
        int p = tileStart + waveM * 64 + m * 16 + (lane >> 4) * 4 + r;
#pragma unroll
        for (int n = 0; n < 4; ++n) {
          int col = tileN + waveN * 64 + n * 16 + (lane & 15);
          ybp[(long)p * ND + col] = f2bf(acc[m][n][r]);
        }
      }
    }
  } else {
    float* outF = (float*)OutP;
#pragma unroll
    for (int m = 0; m < 4; ++m) {
#pragma unroll
      for (int r = 0; r < 4; ++r) {
        int p = tileStart + waveM * 64 + m * 16 + (lane >> 4) * 4 + r;
        int tok = pairTok[p];
        if (tok < 0) continue;
        float wv = pairW[p];
#pragma unroll
        for (int n = 0; n < 4; ++n) {
          int col = tileN + waveN * 64 + n * 16 + (lane & 15);
          atomicAdd(&outF[(long)tok * DN + col], wv * acc[m][n][r]);
        }
      }
    }
  }
}

extern "C" void kernel_launch(void* const* d_in, const int* in_sizes, int n_in,
                              void* d_out, int out_size, void* d_ws, size_t ws_size,
                              hipStream_t stream) {
  const float* x = (const float*)d_in[0];
  const float* rw = (const float*)d_in[1];
  const float* w1 = (const float*)d_in[2];
  const float* w2 = (const float*)d_in[3];
  char* W = (char*)d_ws;
  size_t off = 0;
  auto alloc = [&](size_t sz) {
    off = (off + 255) & ~(size_t)255;
    size_t r = off; off += sz; return r;
  };
  size_t ctrlO = alloc(256);  // cnt[8], cursor[8], poff[9]
  size_t eidsO = alloc((size_t)TN * 2 * 4);
  size_t wtsO  = alloc((size_t)TN * 2 * 4);
  size_t ptokO = alloc((size_t)PADMAX * 4);
  size_t pwO   = alloc((size_t)PADMAX * 4);
  size_t sposO = alloc((size_t)TN * 2 * 4);
  size_t xbO   = alloc((size_t)TN * DN * 2);
  size_t xgO   = alloc((size_t)PADMAX * DN * 2);
  size_t wB = (size_t)EN * HN * DN * 2;
  size_t afterFixed = (off + 255) & ~(size_t)255;
  bool bw = ws_size >= afterFixed + 2 * wB + (size_t)128 * HN * 2 + 4096;
  size_t w1bO = 0, w2bO = 0;
  if (bw) { w1bO = alloc(wB); w2bO = alloc(wB); }
  size_t ybB = (size_t)PADMAX * DN * 2;
  size_t afterW = (off + 255) & ~(size_t)255;
  bool dense = ws_size >= afterW + ybB + (size_t)128 * HN * 2 + 4096;
  size_t ybO = 0;
  if (dense) ybO = alloc(ybB);
  size_t hbase = (off + 255) & ~(size_t)255;
  size_t avail = ws_size > hbase ? ws_size - hbase : (size_t)128 * HN * 2;
  long Cl = (long)(avail / ((size_t)HN * 2));
  if (Cl > PADMAX) Cl = PADMAX;
  Cl &= ~127l;
  if (Cl < 128) Cl = 128;
  int C = (int)Cl;
  size_t hbO = alloc((size_t)C * HN * 2);
  int nCh = (PADMAX + C - 1) / C;

  int* cnt = (int*)(W + ctrlO);
  int* cursor = cnt + 8;
  int* poff = cnt + 16;
  int* eids = (int*)(W + eidsO);
  float* wts = (float*)(W + wtsO);
  int* pairTok = (int*)(W + ptokO);
  float* pairW = (float*)(W + pwO);
  int* slotPos = (int*)(W + sposO);
  unsigned short* xb = (unsigned short*)(W + xbO);
  unsigned short* xg = (unsigned short*)(W + xgO);
  unsigned short* hb = (unsigned short*)(W + hbO);
  unsigned short* yb = (unsigned short*)(W + ybO);

  hipFuncSetAttribute(reinterpret_cast<const void*>(moe_gemm128_k<1, true>),
                      hipFuncAttributeMaxDynamicSharedMemorySize, 65536);
  hipFuncSetAttribute(reinterpret_cast<const void*>(moe_gemm128_k<2, true>),
                      hipFuncAttributeMaxDynamicSharedMemorySize, 65536);
  hipFuncSetAttribute(reinterpret_cast<const void*>(moe_gemm128_k<3, true>),
                      hipFuncAttributeMaxDynamicSharedMemorySize, 65536);
  hipFuncSetAttribute(reinterpret_cast<const void*>(moe_gemm128_k<1, false>),
                      hipFuncAttributeMaxDynamicSharedMemorySize, 65536);
  hipFuncSetAttribute(reinterpret_cast<const void*>(moe_gemm128_k<2, false>),
                      hipFuncAttributeMaxDynamicSharedMemorySize, 65536);
  hipFuncSetAttribute(reinterpret_cast<const void*>(moe_gemm128_k<3, false>),
                      hipFuncAttributeMaxDynamicSharedMemorySize, 65536);

  hipMemsetAsync(W + ctrlO, 0, 256, stream);
  hipMemsetAsync(W + ptokO, 0xFF, (size_t)PADMAX * 4, stream);  // pairTok = -1
  if (!dense) hipMemsetAsync(d_out, 0, (size_t)TN * DN * 4, stream);

  cvt_bf16_k<<<1024, 256, 0, stream>>>(x, xb, (long)TN * DN / 4);
  if (bw) {
    cvt_bf16_k<<<2048, 256, 0, stream>>>(w1, (unsigned short*)(W + w1bO), (long)EN * HN * DN / 4);
    cvt_bf16_k<<<2048, 256, 0, stream>>>(w2, (unsigned short*)(W + w2bO), (long)EN * HN * DN / 4);
  }
  router_k<<<TN / 4, 256, 0, stream>>>(x, rw, eids, wts, cnt);
  offsets_k<<<1, 1, 0, stream>>>(cnt, poff);
  scatter_k<<<TN / 256, 256, 0, stream>>>(eids, wts, poff, cursor, pairTok, pairW, slotPos);
  gather_k<<<PADMAX / 4, 256, 0, stream>>>(xb, pairTok, xg);

  int Ctiles = C / 128;
  for (int c = 0; c < nCh; ++c) {
    int cs = c * C;
    if (bw) {
      moe_gemm128_k<1, true><<<dim3(HN / 128, Ctiles, 1), 256, 65536, stream>>>(
          xg, W + w1bO, hb, pairTok, pairW, poff, cs);
      if (dense) {
        moe_gemm128_k<2, true><<<dim3(DN / 128, Ctiles, 1), 256, 65536, stream>>>(
            hb, W + w2bO, yb, pairTok, pairW, poff, cs);
      } else {
        moe_gemm128_k<3, true><<<dim3(DN / 128, Ctiles, 2), 256, 65536, stream>>>(
            hb, W + w2bO, d_out, pairTok, pairW, poff, cs);
      }
    } else {
      moe_gemm128_k<1, false><<<dim3(HN / 128, Ctiles, 1), 256, 65536, stream>>>(
          xg, w1, hb, pairTok, pairW, poff, cs);
      if (dense) {
        moe_gemm128_k<2, false><<<dim3(DN / 128, Ctiles, 1), 256, 65536, stream>>>(
            hb, w2, yb, pairTok, pairW, poff, cs);
      } else {
        moe_gemm128_k<3, false><<<dim3(DN / 128, Ctiles, 2), 256, 65536, stream>>>(
            hb, w2, d_out, pairTok, pairW, poff, cs);
      }
    }
  }
  if (dense) {
    combine_k<<<TN, 256, 0, stream>>>(yb, wts, slotPos, (float*)d_out);
  }
}

// Round 7
// 754.650 us; speedup vs baseline: 1.2160x; 1.0410x over previous
//
#include <hip/hip_runtime.h>
#include <hip/hip_bf16.h>
#include <cstdint>

#define TN 8192
#define DN 1024
#define HN 4096
#define EN 8
#define PADMAX 18432  // >= 16384 + 8*127 worst-case pad(128), rounded up

typedef __attribute__((ext_vector_type(8))) short short8;
typedef __attribute__((ext_vector_type(4))) float f32x4;
typedef __attribute__((ext_vector_type(4))) unsigned short ushort4v;

__device__ inline unsigned short f2bf(float f) {
  unsigned u = __builtin_bit_cast(unsigned, f);
  u = u + 0x7fffu + ((u >> 16) & 1u);
  return (unsigned short)(u >> 16);
}
__device__ inline float bf2f(unsigned short u) {
  unsigned v = ((unsigned)u) << 16;
  return __builtin_bit_cast(float, v);
}

// exact tanh-GELU identity: 0.5*v*(1+tanh(z)) == v * sigmoid(2z)
__device__ inline float gelu_f(float v) {
  float z2 = 1.5957691216057308f * (v + 0.044715f * v * v * v);
  return v / (1.f + __expf(-z2));
}

__device__ inline void gload_lds16(const void* g, void* l) {
  __builtin_amdgcn_global_load_lds(
      (const __attribute__((address_space(1))) unsigned int*)g,
      (__attribute__((address_space(3))) unsigned int*)l, 16, 0, 0);
}

// both weight tensors in one launch (grid-stride over 2*n4 float4s)
__global__ __launch_bounds__(256) void cvt2_bf16_k(const float* __restrict__ s1,
                                                   const float* __restrict__ s2,
                                                   unsigned short* __restrict__ d1,
                                                   unsigned short* __restrict__ d2,
                                                   long n4) {
  long i = (long)blockIdx.x * blockDim.x + threadIdx.x;
  long stride = (long)gridDim.x * blockDim.x;
  for (; i < 2 * n4; i += stride) {
    const float* s; unsigned short* d; long j;
    if (i < n4) { s = s1; d = d1; j = i; } else { s = s2; d = d2; j = i - n4; }
    float4 v = ((const float4*)s)[j];
    ushort4v o;
    o.x = f2bf(v.x); o.y = f2bf(v.y); o.z = f2bf(v.z); o.w = f2bf(v.w);
    ((ushort4v*)d)[j] = o;
  }
}

__global__ __launch_bounds__(256) void router_k(const float* __restrict__ x,
                                                const float* __restrict__ rw,
                                                int* __restrict__ eids,
                                                float* __restrict__ wts,
                                                int* __restrict__ cnt) {
  int wid = threadIdx.x >> 6, lane = threadIdx.x & 63;
  int t = blockIdx.x * 4 + wid;
  const float* xr = x + (long)t * DN;
  float a[EN];
#pragma unroll
  for (int e = 0; e < EN; ++e) a[e] = 0.f;
  for (int k = lane; k < DN; k += 64) {
    float xv = xr[k];
#pragma unroll
    for (int e = 0; e < EN; ++e) a[e] += xv * rw[e * DN + k];
  }
#pragma unroll
  for (int off = 32; off > 0; off >>= 1) {
#pragma unroll
    for (int e = 0; e < EN; ++e) a[e] += __shfl_xor(a[e], off);
  }
  if (lane == 0) {
    float mx = a[0];
#pragma unroll
    for (int e = 1; e < EN; ++e) mx = fmaxf(mx, a[e]);
    float p[EN], s = 0.f;
#pragma unroll
    for (int e = 0; e < EN; ++e) { p[e] = __expf(a[e] - mx); s += p[e]; }
    int e0 = 0; float b0 = p[0];
#pragma unroll
    for (int e = 1; e < EN; ++e) if (p[e] > b0) { b0 = p[e]; e0 = e; }
    int e1 = -1; float b1 = -1.f;
#pragma unroll
    for (int e = 0; e < EN; ++e) if (e != e0 && p[e] > b1) { b1 = p[e]; e1 = e; }
    float inv = 1.f / s;
    eids[2 * t] = e0; eids[2 * t + 1] = e1;
    wts[2 * t] = b0 * inv; wts[2 * t + 1] = b1 * inv;
    atomicAdd(&cnt[e0], 1);
    atomicAdd(&cnt[e1], 1);
  }
}

__global__ void offsets_k(const int* __restrict__ cnt, int* __restrict__ poff) {
  if (threadIdx.x == 0 && blockIdx.x == 0) {
    int o = 0;
    for (int e = 0; e < EN; ++e) { poff[e] = o; o += (cnt[e] + 127) & ~127; }
    poff[EN] = o;
  }
}

__global__ __launch_bounds__(256) void scatter_k(const int* __restrict__ eids,
                                                 const float* __restrict__ wts,
                                                 const int* __restrict__ poff,
                                                 int* __restrict__ cursor,
                                                 int* __restrict__ pairTok,
                                                 float* __restrict__ pairW,
                                                 int* __restrict__ slotPos) {
  int t = blockIdx.x * 256 + threadIdx.x;
#pragma unroll
  for (int k = 0; k < 2; ++k) {
    int e = eids[2 * t + k];
    int p = atomicAdd(&cursor[e], 1);
    int pos = poff[e] + p;
    pairTok[pos] = t;
    pairW[pos] = wts[2 * t + k];
    slotPos[2 * t + k] = pos;
  }
}

// xg[pos] = bf16(x[pairTok[pos]]) : gather + convert in one pass (fp32 source)
__global__ __launch_bounds__(256) void gather_k(const float* __restrict__ x,
                                                const int* __restrict__ pairTok,
                                                unsigned short* __restrict__ xg) {
  int p = blockIdx.x * 4 + (threadIdx.x >> 6);
  int lane = threadIdx.x & 63;
  int tok = pairTok[p];
  if (tok < 0) tok = 0;
  const float4* src = (const float4*)(x + (long)tok * DN);
  ushort4v* dst = (ushort4v*)(xg + (long)p * DN);
#pragma unroll
  for (int j = 0; j < 4; ++j) {
    float4 v = src[j * 64 + lane];
    ushort4v o;
    o.x = f2bf(v.x); o.y = f2bf(v.y); o.z = f2bf(v.z); o.w = f2bf(v.w);
    dst[j * 64 + lane] = o;
  }
}

// out[t] = w0 * yb[pos0] + w1 * yb[pos1]
__global__ __launch_bounds__(256) void combine_k(const unsigned short* __restrict__ yb,
                                                 const float* __restrict__ wts,
                                                 const int* __restrict__ slotPos,
                                                 float* __restrict__ out) {
  int t = blockIdx.x;
  int p0 = slotPos[2 * t], p1 = slotPos[2 * t + 1];
  float w0 = wts[2 * t], w1 = wts[2 * t + 1];
  int c = threadIdx.x * 4;
  ushort4v y0 = *(const ushort4v*)(yb + (long)p0 * DN + c);
  ushort4v y1 = *(const ushort4v*)(yb + (long)p1 * DN + c);
  float4 o;
  o.x = w0 * bf2f(y0.x) + w1 * bf2f(y1.x);
  o.y = w0 * bf2f(y0.y) + w1 * bf2f(y1.y);
  o.z = w0 * bf2f(y0.z) + w1 * bf2f(y1.z);
  o.w = w0 * bf2f(y0.w) + w1 * bf2f(y1.w);
  *(float4*)(out + (long)t * DN + c) = o;
}

// ---- 128x128 GEMM, BK=64, 4 waves (2x2), 64 KiB LDS dbuf -> 2 blocks/CU ----
// MODE 1: h = gelu(xg @ w1[e]^T)   A linear (pre-gathered), K=1024, N=4096
// MODE 2: yb = h @ w2[e]^T         A linear (chunk-local),  K=4096, N=1024
// MODE 3: fallback atomics with split-K 2

#define BAR() { asm volatile("" ::: "memory"); __builtin_amdgcn_s_barrier(); \
                asm volatile("" ::: "memory"); }
#define LGKM0() { asm volatile("s_waitcnt lgkmcnt(0)" ::: "memory"); }

#define LDA4(PAR) { const char* _b = smem + (PAR)*16384;                             \
  _Pragma("unroll") for (int m = 0; m < 4; ++m) {                                    \
    int row = waveM*64 + m*16 + (lane & 15); int cb = row * 128;                     \
    a[m][0] = *(const short8*)(_b + cb + (((lane>>4) ^ (row&7)) * 16));              \
    a[m][1] = *(const short8*)(_b + cb + (((4 + (lane>>4)) ^ (row&7)) * 16)); } }

#define LDB2(NH, PAR) { const char* _b = smem + 32768 + (PAR)*16384;                 \
  _Pragma("unroll") for (int n = 0; n < 2; ++n) {                                    \
    int row = waveN*64 + ((NH)*2+n)*16 + (lane & 15); int cb = row * 128;            \
    b[(NH)*2+n][0] = *(const short8*)(_b + cb + (((lane>>4) ^ (row&7)) * 16));       \
    b[(NH)*2+n][1] = *(const short8*)(_b + cb + (((4 + (lane>>4)) ^ (row&7)) * 16)); } }

#define MM16(NH) { __builtin_amdgcn_s_setprio(1);                                    \
  _Pragma("unroll") for (int m = 0; m < 4; ++m)                                      \
    _Pragma("unroll") for (int n = 0; n < 2; ++n) {                                  \
      acc[m][(NH)*2+n] = __builtin_amdgcn_mfma_f32_16x16x32_bf16(                    \
          a[m][0], b[(NH)*2+n][0], acc[m][(NH)*2+n], 0, 0, 0);                       \
      acc[m][(NH)*2+n] = __builtin_amdgcn_mfma_f32_16x16x32_bf16(                    \
          a[m][1], b[(NH)*2+n][1], acc[m][(NH)*2+n], 0, 0, 0); }                     \
  __builtin_amdgcn_s_setprio(0); }

template <int MODE, bool BBF16>
__global__ __launch_bounds__(256, 2) void moe_gemm128_k(
    const unsigned short* __restrict__ Ab, const void* __restrict__ Bsrc,
    void* __restrict__ OutP, const int* __restrict__ pairTok,
    const float* __restrict__ pairW, const int* __restrict__ poff, int chunkStart) {
  constexpr int KD = (MODE == 1) ? DN : HN;
  constexpr int ND = (MODE == 1) ? HN : DN;
  constexpr int SPLIT = (MODE == 3) ? 2 : 1;
  constexpr int KLEN = KD / SPLIT;
  constexpr int NT = KLEN / 64;

  extern __shared__ char smem[];

  // T1: bijective XCD swizzle over (x,y)
  int NX = gridDim.x;
  int NXY = NX * gridDim.y;
  int orig = blockIdx.y * NX + blockIdx.x;
  int qq = NXY >> 3, rrm = NXY & 7;
  int xcd = orig & 7, pos = orig >> 3;
  int wg = (xcd < rrm ? xcd * (qq + 1) : rrm * (qq + 1) + (xcd - rrm) * qq) + pos;
  int tileN = (wg % NX) * 128;
  int tileStart = chunkStart + (wg / NX) * 128;

  int Ppad = poff[EN];
  if (tileStart >= Ppad) return;
  int e = 0;
  while (e < EN - 1 && tileStart >= poff[e + 1]) ++e;

  int tid = threadIdx.x;
  int wid = tid >> 6, lane = tid & 63;
  int waveM = wid >> 1, waveN = wid & 1;
  int kbase = (MODE == 3) ? blockIdx.z * KLEN : 0;

  int r0 = tid >> 3;
  const char* aSrc[4];
  const char* bSrc[4];
#pragma unroll
  for (int j = 0; j < 4; ++j) {
    int row = j * 32 + r0;
    int s = (tid & 7) ^ (row & 7);
    long abase = (MODE == 1) ? (long)(tileStart + row) * KD
                             : (long)(tileStart - chunkStart + row) * KD;
    aSrc[j] = (const char*)(Ab + abase + kbase + s * 8);
    long bb = (long)e * ND * KD + (long)(tileN + row) * KD + kbase + s * 8;
    bSrc[j] = (const char*)Bsrc + bb * (BBF16 ? 2 : 4);
  }

  auto stageA = [&](int k0, int par) {
#pragma unroll
    for (int j = 0; j < 4; ++j)
      gload_lds16(aSrc[j] + (long)k0 * 2, smem + par * 16384 + (j * 256 + tid) * 16);
  };
  auto stageB = [&](int k0, int par) {
    if constexpr (BBF16) {
#pragma unroll
      for (int j = 0; j < 4; ++j)
        gload_lds16(bSrc[j] + (long)k0 * 2, smem + 32768 + par * 16384 + (j * 256 + tid) * 16);
    } else {
#pragma unroll
      for (int j = 0; j < 4; ++j) {
        const float4* pf = (const float4*)(bSrc[j] + (long)k0 * 4);
        float4 v0 = pf[0], v1 = pf[1];
        short8 pk;
        pk[0] = (short)f2bf(v0.x); pk[1] = (short)f2bf(v0.y);
        pk[2] = (short)f2bf(v0.z); pk[3] = (short)f2bf(v0.w);
        pk[4] = (short)f2bf(v1.x); pk[5] = (short)f2bf(v1.y);
        pk[6] = (short)f2bf(v1.z); pk[7] = (short)f2bf(v1.w);
        *(short8*)(smem + 32768 + par * 16384 + (j * 256 + tid) * 16) = pk;
      }
    }
  };

  f32x4 acc[4][4];
#pragma unroll
  for (int m = 0; m < 4; ++m)
#pragma unroll
    for (int n = 0; n < 4; ++n) acc[m][n] = (f32x4){0.f, 0.f, 0.f, 0.f};
  short8 a[4][2], b[4][2];

  // prologue: tile0 -> buf0, tile1 -> buf1 (16 loads); keep tile1's 8 in flight
  stageA(0, 0); stageB(0, 0);
  stageA(64, 1); stageB(64, 1);
  if constexpr (BBF16) {
    asm volatile("s_waitcnt vmcnt(8)" ::: "memory");
  } else {
    asm volatile("s_waitcnt vmcnt(0) lgkmcnt(0)" ::: "memory");
  }
  BAR();

  for (int t = 0; t < NT; ++t) {
    int P = t & 1;
    int k2 = (t + 2) * 64;
    // ph1
    LDA4(P); LDB2(0, P);
    BAR(); LGKM0();
    MM16(0);
    BAR();
    // ph2 (A[P] reads done -> overwrite A[P] with tile t+2)
    LDB2(1, P);
    if (t + 2 < NT) stageA(k2, P);
    BAR(); LGKM0();
    MM16(1);
    // tail (B[P] reads done -> stage B(t+2))
    if (t + 2 < NT) stageB(k2, P);
    if (BBF16 && t + 2 < NT) {
      asm volatile("s_waitcnt vmcnt(8)" ::: "memory");
    } else {
      asm volatile("s_waitcnt vmcnt(0)" ::: "memory");
    }
    BAR();
  }

  if (MODE == 1) {
    unsigned short* hbp = (unsigned short*)OutP;
    int rl0 = tileStart - chunkStart + waveM * 64;
#pragma unroll
    for (int m = 0; m < 4; ++m) {
#pragma unroll
      for (int r = 0; r < 4; ++r) {
        int rl = rl0 + m * 16 + (lane >> 4) * 4 + r;
#pragma unroll
        for (int n = 0; n < 4; ++n) {
          int col = tileN + waveN * 64 + n * 16 + (lane & 15);
          hbp[(long)rl * HN + col] = f2bf(gelu_f(acc[m][n][r]));
        }
      }
    }
  } else if (MODE == 2) {
    unsigned short* ybp = (unsigned short*)OutP;
#pragma unroll
    for (int m = 0; m < 4; ++m) {
#pragma unroll
      for (int r = 0; r < 4; ++r) {
        int p = tileStart + waveM * 64 + m * 16 + (lane >> 4) * 4 + r;
#pragma unroll
        for (int n = 0; n < 4; ++n) {
          int col = tileN + waveN * 64 + n * 16 + (lane & 15);
          ybp[(long)p * ND + col] = f2bf(acc[m][n][r]);
        }
      }
    }
  } else {
    float* outF = (float*)OutP;
#pragma unroll
    for (int m = 0; m < 4; ++m) {
#pragma unroll
      for (int r = 0; r < 4; ++r) {
        int p = tileStart + waveM * 64 + m * 16 + (lane >> 4) * 4 + r;
        int tok = pairTok[p];
        if (tok < 0) continue;
        float wv = pairW[p];
#pragma unroll
        for (int n = 0; n < 4; ++n) {
          int col = tileN + waveN * 64 + n * 16 + (lane & 15);
          atomicAdd(&outF[(long)tok * DN + col], wv * acc[m][n][r]);
        }
      }
    }
  }
}

extern "C" void kernel_launch(void* const* d_in, const int* in_sizes, int n_in,
                              void* d_out, int out_size, void* d_ws, size_t ws_size,
                              hipStream_t stream) {
  const float* x = (const float*)d_in[0];
  const float* rw = (const float*)d_in[1];
  const float* w1 = (const float*)d_in[2];
  const float* w2 = (const float*)d_in[3];
  char* W = (char*)d_ws;
  size_t off = 0;
  auto alloc = [&](size_t sz) {
    off = (off + 255) & ~(size_t)255;
    size_t r = off; off += sz; return r;
  };
  size_t ctrlO = alloc(256);  // cnt[8], cursor[8], poff[9]
  size_t eidsO = alloc((size_t)TN * 2 * 4);
  size_t wtsO  = alloc((size_t)TN * 2 * 4);
  size_t ptokO = alloc((size_t)PADMAX * 4);
  size_t pwO   = alloc((size_t)PADMAX * 4);
  size_t sposO = alloc((size_t)TN * 2 * 4);
  size_t xgO   = alloc((size_t)PADMAX * DN * 2);
  size_t wB = (size_t)EN * HN * DN * 2;
  size_t afterFixed = (off + 255) & ~(size_t)255;
  bool bw = ws_size >= afterFixed + 2 * wB + (size_t)128 * HN * 2 + 4096;
  size_t w1bO = 0, w2bO = 0;
  if (bw) { w1bO = alloc(wB); w2bO = alloc(wB); }
  size_t ybB = (size_t)PADMAX * DN * 2;
  size_t afterW = (off + 255) & ~(size_t)255;
  bool dense = ws_size >= afterW + ybB + (size_t)128 * HN * 2 + 4096;
  size_t ybO = 0;
  if (dense) ybO = alloc(ybB);
  size_t hbase = (off + 255) & ~(size_t)255;
  size_t avail = ws_size > hbase ? ws_size - hbase : (size_t)128 * HN * 2;
  long Cl = (long)(avail / ((size_t)HN * 2));
  if (Cl > PADMAX) Cl = PADMAX;
  Cl &= ~127l;
  if (Cl < 128) Cl = 128;
  int C = (int)Cl;
  size_t hbO = alloc((size_t)C * HN * 2);
  int nCh = (PADMAX + C - 1) / C;

  int* cnt = (int*)(W + ctrlO);
  int* cursor = cnt + 8;
  int* poff = cnt + 16;
  int* eids = (int*)(W + eidsO);
  float* wts = (float*)(W + wtsO);
  int* pairTok = (int*)(W + ptokO);
  float* pairW = (float*)(W + pwO);
  int* slotPos = (int*)(W + sposO);
  unsigned short* xg = (unsigned short*)(W + xgO);
  unsigned short* hb = (unsigned short*)(W + hbO);
  unsigned short* yb = (unsigned short*)(W + ybO);

  hipFuncSetAttribute(reinterpret_cast<const void*>(moe_gemm128_k<1, true>),
                      hipFuncAttributeMaxDynamicSharedMemorySize, 65536);
  hipFuncSetAttribute(reinterpret_cast<const void*>(moe_gemm128_k<2, true>),
                      hipFuncAttributeMaxDynamicSharedMemorySize, 65536);
  hipFuncSetAttribute(reinterpret_cast<const void*>(moe_gemm128_k<3, true>),
                      hipFuncAttributeMaxDynamicSharedMemorySize, 65536);
  hipFuncSetAttribute(reinterpret_cast<const void*>(moe_gemm128_k<1, false>),
                      hipFuncAttributeMaxDynamicSharedMemorySize, 65536);
  hipFuncSetAttribute(reinterpret_cast<const void*>(moe_gemm128_k<2, false>),
                      hipFuncAttributeMaxDynamicSharedMemorySize, 65536);
  hipFuncSetAttribute(reinterpret_cast<const void*>(moe_gemm128_k<3, false>),
                      hipFuncAttributeMaxDynamicSharedMemorySize, 65536);

  hipMemsetAsync(W + ctrlO, 0, 256, stream);
  hipMemsetAsync(W + ptokO, 0xFF, (size_t)PADMAX * 4, stream);  // pairTok = -1
  if (!dense) hipMemsetAsync(d_out, 0, (size_t)TN * DN * 4, stream);

  if (bw) {
    cvt2_bf16_k<<<4096, 256, 0, stream>>>(w1, w2, (unsigned short*)(W + w1bO),
                                          (unsigned short*)(W + w2bO),
                                          (long)EN * HN * DN / 4);
  }
  router_k<<<TN / 4, 256, 0, stream>>>(x, rw, eids, wts, cnt);
  offsets_k<<<1, 1, 0, stream>>>(cnt, poff);
  scatter_k<<<TN / 256, 256, 0, stream>>>(eids, wts, poff, cursor, pairTok, pairW, slotPos);
  gather_k<<<PADMAX / 4, 256, 0, stream>>>(x, pairTok, xg);

  int Ctiles = C / 128;
  for (int c = 0; c < nCh; ++c) {
    int cs = c * C;
    if (bw) {
      moe_gemm128_k<1, true><<<dim3(HN / 128, Ctiles, 1), 256, 65536, stream>>>(
          xg, W + w1bO, hb, pairTok, pairW, poff, cs);
      if (dense) {
        moe_gemm128_k<2, true><<<dim3(DN / 128, Ctiles, 1), 256, 65536, stream>>>(
            hb, W + w2bO, yb, pairTok, pairW, poff, cs);
      } else {
        moe_gemm128_k<3, true><<<dim3(DN / 128, Ctiles, 2), 256, 65536, stream>>>(
            hb, W + w2bO, d_out, pairTok, pairW, poff, cs);
      }
    } else {
      moe_gemm128_k<1, false><<<dim3(HN / 128, Ctiles, 1), 256, 65536, stream>>>(
          xg, w1, hb, pairTok, pairW, poff, cs);
      if (dense) {
        moe_gemm128_k<2, false><<<dim3(DN / 128, Ctiles, 1), 256, 65536, stream>>>(
            hb, w2, yb, pairTok, pairW, poff, cs);
      } else {
        moe_gemm128_k<3, false><<<dim3(DN / 128, Ctiles, 2), 256, 65536, stream>>>(
            hb, w2, d_out, pairTok, pairW, poff, cs);
      }
    }
  }
  if (dense) {
    combine_k<<<TN, 256, 0, stream>>>(yb, wts, slotPos, (float*)d_out);
  }
}

// Round 8
// 720.522 us; speedup vs baseline: 1.2736x; 1.0474x over previous
//
#include <hip/hip_runtime.h>
#include <hip/hip_bf16.h>
#include <cstdint>

#define TN 8192
#define DN 1024
#define HN 4096
#define EN 8
#define PADMAX 18432  // >= 16384 + 8*127 worst-case pad(128), rounded up

typedef __attribute__((ext_vector_type(8))) short short8;
typedef __attribute__((ext_vector_type(4))) float f32x4;
typedef __attribute__((ext_vector_type(4))) unsigned short ushort4v;

__device__ inline unsigned short f2bf(float f) {
  unsigned u = __builtin_bit_cast(unsigned, f);
  u = u + 0x7fffu + ((u >> 16) & 1u);
  return (unsigned short)(u >> 16);
}
__device__ inline float bf2f(unsigned short u) {
  unsigned v = ((unsigned)u) << 16;
  return __builtin_bit_cast(float, v);
}

// exact tanh-GELU identity: 0.5*v*(1+tanh(z)) == v * sigmoid(2z)
__device__ inline float gelu_f(float v) {
  float z2 = 1.5957691216057308f * (v + 0.044715f * v * v * v);
  return v / (1.f + __expf(-z2));
}

__device__ inline void gload_lds16(const void* g, void* l) {
  __builtin_amdgcn_global_load_lds(
      (const __attribute__((address_space(1))) unsigned int*)g,
      (__attribute__((address_space(3))) unsigned int*)l, 16, 0, 0);
}

// fused: blocks [0,2048) = router (4 tokens/block); blocks [2048,..) = weight cvt
__global__ __launch_bounds__(256) void prep_k(const float* __restrict__ x,
                                              const float* __restrict__ rw,
                                              const float* __restrict__ w1,
                                              const float* __restrict__ w2,
                                              unsigned short* __restrict__ w1b,
                                              unsigned short* __restrict__ w2b,
                                              int* __restrict__ eids,
                                              float* __restrict__ wts,
                                              int* __restrict__ cnt,
                                              int nCvtBlk, long n4) {
  if (blockIdx.x < TN / 4) {
    int wid = threadIdx.x >> 6, lane = threadIdx.x & 63;
    int t = blockIdx.x * 4 + wid;
    const float* xr = x + (long)t * DN;
    float a[EN];
#pragma unroll
    for (int e = 0; e < EN; ++e) a[e] = 0.f;
    for (int k = lane; k < DN; k += 64) {
      float xv = xr[k];
#pragma unroll
      for (int e = 0; e < EN; ++e) a[e] += xv * rw[e * DN + k];
    }
#pragma unroll
    for (int off = 32; off > 0; off >>= 1) {
#pragma unroll
      for (int e = 0; e < EN; ++e) a[e] += __shfl_xor(a[e], off);
    }
    if (lane == 0) {
      float mx = a[0];
#pragma unroll
      for (int e = 1; e < EN; ++e) mx = fmaxf(mx, a[e]);
      float p[EN], s = 0.f;
#pragma unroll
      for (int e = 0; e < EN; ++e) { p[e] = __expf(a[e] - mx); s += p[e]; }
      int e0 = 0; float b0 = p[0];
#pragma unroll
      for (int e = 1; e < EN; ++e) if (p[e] > b0) { b0 = p[e]; e0 = e; }
      int e1 = -1; float b1 = -1.f;
#pragma unroll
      for (int e = 0; e < EN; ++e) if (e != e0 && p[e] > b1) { b1 = p[e]; e1 = e; }
      float inv = 1.f / s;
      eids[2 * t] = e0; eids[2 * t + 1] = e1;
      wts[2 * t] = b0 * inv; wts[2 * t + 1] = b1 * inv;
      atomicAdd(&cnt[e0], 1);
      atomicAdd(&cnt[e1], 1);
    }
  } else {
    long i = (long)(blockIdx.x - TN / 4) * blockDim.x + threadIdx.x;
    long stride = (long)nCvtBlk * blockDim.x;
    for (; i < 2 * n4; i += stride) {
      const float* s; unsigned short* d; long j;
      if (i < n4) { s = w1; d = w1b; j = i; } else { s = w2; d = w2b; j = i - n4; }
      float4 v = ((const float4*)s)[j];
      ushort4v o;
      o.x = f2bf(v.x); o.y = f2bf(v.y); o.z = f2bf(v.z); o.w = f2bf(v.w);
      ((ushort4v*)d)[j] = o;
    }
  }
}

__global__ void offsets_k(const int* __restrict__ cnt, int* __restrict__ poff) {
  if (threadIdx.x == 0 && blockIdx.x == 0) {
    int o = 0;
    for (int e = 0; e < EN; ++e) { poff[e] = o; o += (cnt[e] + 127) & ~127; }
    poff[EN] = o;
  }
}

__global__ __launch_bounds__(256) void scatter_k(const int* __restrict__ eids,
                                                 const float* __restrict__ wts,
                                                 const int* __restrict__ poff,
                                                 int* __restrict__ cursor,
                                                 int* __restrict__ pairTok,
                                                 float* __restrict__ pairW,
                                                 int* __restrict__ slotPos) {
  int t = blockIdx.x * 256 + threadIdx.x;
#pragma unroll
  for (int k = 0; k < 2; ++k) {
    int e = eids[2 * t + k];
    int p = atomicAdd(&cursor[e], 1);
    int pos = poff[e] + p;
    pairTok[pos] = t;
    pairW[pos] = wts[2 * t + k];
    slotPos[2 * t + k] = pos;
  }
}

// xg[pos] = bf16(x[pairTok[pos]]) : gather + convert in one pass (fp32 source)
__global__ __launch_bounds__(256) void gather_k(const float* __restrict__ x,
                                                const int* __restrict__ pairTok,
                                                unsigned short* __restrict__ xg) {
  int p = blockIdx.x * 4 + (threadIdx.x >> 6);
  int lane = threadIdx.x & 63;
  int tok = pairTok[p];
  if (tok < 0) tok = 0;
  const float4* src = (const float4*)(x + (long)tok * DN);
  ushort4v* dst = (ushort4v*)(xg + (long)p * DN);
#pragma unroll
  for (int j = 0; j < 4; ++j) {
    float4 v = src[j * 64 + lane];
    ushort4v o;
    o.x = f2bf(v.x); o.y = f2bf(v.y); o.z = f2bf(v.z); o.w = f2bf(v.w);
    dst[j * 64 + lane] = o;
  }
}

// out[t] = w0 * yb[pos0] + w1 * yb[pos1]
__global__ __launch_bounds__(256) void combine_k(const unsigned short* __restrict__ yb,
                                                 const float* __restrict__ wts,
                                                 const int* __restrict__ slotPos,
                                                 float* __restrict__ out) {
  int t = blockIdx.x;
  int p0 = slotPos[2 * t], p1 = slotPos[2 * t + 1];
  float w0 = wts[2 * t], w1 = wts[2 * t + 1];
  int c = threadIdx.x * 4;
  ushort4v y0 = *(const ushort4v*)(yb + (long)p0 * DN + c);
  ushort4v y1 = *(const ushort4v*)(yb + (long)p1 * DN + c);
  float4 o;
  o.x = w0 * bf2f(y0.x) + w1 * bf2f(y1.x);
  o.y = w0 * bf2f(y0.y) + w1 * bf2f(y1.y);
  o.z = w0 * bf2f(y0.z) + w1 * bf2f(y1.z);
  o.w = w0 * bf2f(y0.w) + w1 * bf2f(y1.w);
  *(float4*)(out + (long)t * DN + c) = o;
}

// ---- 128x128 GEMM, BK=64, 4 waves (2x2), 64 KiB LDS dbuf -> 2 blocks/CU ----
// MODE 1: h = gelu(xg @ w1[e]^T)   A linear (pre-gathered), K=1024, N=4096
// MODE 2: yb = h @ w2[e]^T         A linear (chunk-local),  K=4096, N=1024
// MODE 3: fallback atomics with split-K 2
// R8: 2-D group tiling (GH=8 row-tiles per column sweep) for L2 locality.

#define BAR() { asm volatile("" ::: "memory"); __builtin_amdgcn_s_barrier(); \
                asm volatile("" ::: "memory"); }
#define LGKM0() { asm volatile("s_waitcnt lgkmcnt(0)" ::: "memory"); }

#define LDA4(PAR) { const char* _b = smem + (PAR)*16384;                             \
  _Pragma("unroll") for (int m = 0; m < 4; ++m) {                                    \
    int row = waveM*64 + m*16 + (lane & 15); int cb = row * 128;                     \
    a[m][0] = *(const short8*)(_b + cb + (((lane>>4) ^ (row&7)) * 16));              \
    a[m][1] = *(const short8*)(_b + cb + (((4 + (lane>>4)) ^ (row&7)) * 16)); } }

#define LDB2(NH, PAR) { const char* _b = smem + 32768 + (PAR)*16384;                 \
  _Pragma("unroll") for (int n = 0; n < 2; ++n) {                                    \
    int row = waveN*64 + ((NH)*2+n)*16 + (lane & 15); int cb = row * 128;            \
    b[(NH)*2+n][0] = *(const short8*)(_b + cb + (((lane>>4) ^ (row&7)) * 16));       \
    b[(NH)*2+n][1] = *(const short8*)(_b + cb + (((4 + (lane>>4)) ^ (row&7)) * 16)); } }

#define MM16(NH) { __builtin_amdgcn_s_setprio(1);                                    \
  _Pragma("unroll") for (int m = 0; m < 4; ++m)                                      \
    _Pragma("unroll") for (int n = 0; n < 2; ++n) {                                  \
      acc[m][(NH)*2+n] = __builtin_amdgcn_mfma_f32_16x16x32_bf16(                    \
          a[m][0], b[(NH)*2+n][0], acc[m][(NH)*2+n], 0, 0, 0);                       \
      acc[m][(NH)*2+n] = __builtin_amdgcn_mfma_f32_16x16x32_bf16(                    \
          a[m][1], b[(NH)*2+n][1], acc[m][(NH)*2+n], 0, 0, 0); }                     \
  __builtin_amdgcn_s_setprio(0); }

template <int MODE, bool BBF16>
__global__ __launch_bounds__(256, 2) void moe_gemm128_k(
    const unsigned short* __restrict__ Ab, const void* __restrict__ Bsrc,
    void* __restrict__ OutP, const int* __restrict__ pairTok,
    const float* __restrict__ pairW, const int* __restrict__ poff, int chunkStart) {
  constexpr int KD = (MODE == 1) ? DN : HN;
  constexpr int ND = (MODE == 1) ? HN : DN;
  constexpr int SPLIT = (MODE == 3) ? 2 : 1;
  constexpr int KLEN = KD / SPLIT;
  constexpr int NT = KLEN / 64;

  extern __shared__ char smem[];

  // T1: bijective XCD swizzle over (x,y)
  int NX = gridDim.x;
  int NXY = NX * gridDim.y;
  int orig = blockIdx.y * NX + blockIdx.x;
  int qq = NXY >> 3, rrm = NXY & 7;
  int xcd = orig & 7, pos = orig >> 3;
  int wg = (xcd < rrm ? xcd * (qq + 1) : rrm * (qq + 1) + (xcd - rrm) * qq) + pos;

  // 2-D group tiling: sweep GH row-tiles per column before advancing column
  int NYt = NXY / NX;
  const int GH = 8;
  int npg = GH * NX;
  int gid = wg / npg;
  int rem = wg - gid * npg;
  int rowsLeft = NYt - gid * GH;
  int gh = rowsLeft < GH ? rowsLeft : GH;
  int row = gid * GH + rem % gh;
  int col = rem / gh;
  int tileN = col * 128;
  int tileStart = chunkStart + row * 128;

  int Ppad = poff[EN];
  if (tileStart >= Ppad) return;
  int e = 0;
  while (e < EN - 1 && tileStart >= poff[e + 1]) ++e;

  int tid = threadIdx.x;
  int wid = tid >> 6, lane = tid & 63;
  int waveM = wid >> 1, waveN = wid & 1;
  int kbase = (MODE == 3) ? blockIdx.z * KLEN : 0;

  int r0 = tid >> 3;
  const char* aSrc[4];
  const char* bSrc[4];
#pragma unroll
  for (int j = 0; j < 4; ++j) {
    int rw_ = j * 32 + r0;
    int s = (tid & 7) ^ (rw_ & 7);
    long abase = (MODE == 1) ? (long)(tileStart + rw_) * KD
                             : (long)(tileStart - chunkStart + rw_) * KD;
    aSrc[j] = (const char*)(Ab + abase + kbase + s * 8);
    long bb = (long)e * ND * KD + (long)(tileN + rw_) * KD + kbase + s * 8;
    bSrc[j] = (const char*)Bsrc + bb * (BBF16 ? 2 : 4);
  }

  auto stageA = [&](int k0, int par) {
#pragma unroll
    for (int j = 0; j < 4; ++j)
      gload_lds16(aSrc[j] + (long)k0 * 2, smem + par * 16384 + (j * 256 + tid) * 16);
  };
  auto stageB = [&](int k0, int par) {
    if constexpr (BBF16) {
#pragma unroll
      for (int j = 0; j < 4; ++j)
        gload_lds16(bSrc[j] + (long)k0 * 2, smem + 32768 + par * 16384 + (j * 256 + tid) * 16);
    } else {
#pragma unroll
      for (int j = 0; j < 4; ++j) {
        const float4* pf = (const float4*)(bSrc[j] + (long)k0 * 4);
        float4 v0 = pf[0], v1 = pf[1];
        short8 pk;
        pk[0] = (short)f2bf(v0.x); pk[1] = (short)f2bf(v0.y);
        pk[2] = (short)f2bf(v0.z); pk[3] = (short)f2bf(v0.w);
        pk[4] = (short)f2bf(v1.x); pk[5] = (short)f2bf(v1.y);
        pk[6] = (short)f2bf(v1.z); pk[7] = (short)f2bf(v1.w);
        *(short8*)(smem + 32768 + par * 16384 + (j * 256 + tid) * 16) = pk;
      }
    }
  };

  f32x4 acc[4][4];
#pragma unroll
  for (int m = 0; m < 4; ++m)
#pragma unroll
    for (int n = 0; n < 4; ++n) acc[m][n] = (f32x4){0.f, 0.f, 0.f, 0.f};
  short8 a[4][2], b[4][2];

  // prologue: tile0 -> buf0, tile1 -> buf1 (16 loads); keep tile1's 8 in flight
  stageA(0, 0); stageB(0, 0);
  stageA(64, 1); stageB(64, 1);
  if constexpr (BBF16) {
    asm volatile("s_waitcnt vmcnt(8)" ::: "memory");
  } else {
    asm volatile("s_waitcnt vmcnt(0) lgkmcnt(0)" ::: "memory");
  }
  BAR();

  for (int t = 0; t < NT; ++t) {
    int P = t & 1;
    int k2 = (t + 2) * 64;
    // ph1
    LDA4(P); LDB2(0, P);
    BAR(); LGKM0();
    MM16(0);
    BAR();
    // ph2 (A[P] reads done -> overwrite A[P] with tile t+2)
    LDB2(1, P);
    if (t + 2 < NT) stageA(k2, P);
    BAR(); LGKM0();
    MM16(1);
    // tail (B[P] reads done -> stage B(t+2))
    if (t + 2 < NT) stageB(k2, P);
    if (BBF16 && t + 2 < NT) {
      asm volatile("s_waitcnt vmcnt(8)" ::: "memory");
    } else {
      asm volatile("s_waitcnt vmcnt(0)" ::: "memory");
    }
    BAR();
  }

  if (MODE == 1) {
    unsigned short* hbp = (unsigned short*)OutP;
    int rl0 = tileStart - chunkStart + waveM * 64;
#pragma unroll
    for (int m = 0; m < 4; ++m) {
#pragma unroll
      for (int r = 0; r < 4; ++r) {
        int rl = rl0 + m * 16 + (lane >> 4) * 4 + r;
#pragma unroll
        for (int n = 0; n < 4; ++n) {
          int coln = tileN + waveN * 64 + n * 16 + (lane & 15);
          hbp[(long)rl * HN + coln] = f2bf(gelu_f(acc[m][n][r]));
        }
      }
    }
  } else if (MODE == 2) {
    unsigned short* ybp = (unsigned short*)OutP;
#pragma unroll
    for (int m = 0; m < 4; ++m) {
#pragma unroll
      for (int r = 0; r < 4; ++r) {
        int p = tileStart + waveM * 64 + m * 16 + (lane >> 4) * 4 + r;
#pragma unroll
        for (int n = 0; n < 4; ++n) {
          int coln = tileN + waveN * 64 + n * 16 + (lane & 15);
          ybp[(long)p * ND + coln] = f2bf(acc[m][n][r]);
        }
      }
    }
  } else {
    float* outF = (float*)OutP;
#pragma unroll
    for (int m = 0; m < 4; ++m) {
#pragma unroll
      for (int r = 0; r < 4; ++r) {
        int p = tileStart + waveM * 64 + m * 16 + (lane >> 4) * 4 + r;
        int tok = pairTok[p];
        if (tok < 0) continue;
        float wv = pairW[p];
#pragma unroll
        for (int n = 0; n < 4; ++n) {
          int coln = tileN + waveN * 64 + n * 16 + (lane & 15);
          atomicAdd(&outF[(long)tok * DN + coln], wv * acc[m][n][r]);
        }
      }
    }
  }
}

extern "C" void kernel_launch(void* const* d_in, const int* in_sizes, int n_in,
                              void* d_out, int out_size, void* d_ws, size_t ws_size,
                              hipStream_t stream) {
  const float* x = (const float*)d_in[0];
  const float* rw = (const float*)d_in[1];
  const float* w1 = (const float*)d_in[2];
  const float* w2 = (const float*)d_in[3];
  char* W = (char*)d_ws;
  size_t off = 0;
  auto alloc = [&](size_t sz) {
    off = (off + 255) & ~(size_t)255;
    size_t r = off; off += sz; return r;
  };
  size_t ctrlO = alloc(256);  // cnt[8], cursor[8], poff[9]
  size_t eidsO = alloc((size_t)TN * 2 * 4);
  size_t wtsO  = alloc((size_t)TN * 2 * 4);
  size_t ptokO = alloc((size_t)PADMAX * 4);
  size_t pwO   = alloc((size_t)PADMAX * 4);
  size_t sposO = alloc((size_t)TN * 2 * 4);
  size_t xgO   = alloc((size_t)PADMAX * DN * 2);
  size_t wB = (size_t)EN * HN * DN * 2;
  size_t afterFixed = (off + 255) & ~(size_t)255;
  bool bw = ws_size >= afterFixed + 2 * wB + (size_t)128 * HN * 2 + 4096;
  size_t w1bO = 0, w2bO = 0;
  if (bw) { w1bO = alloc(wB); w2bO = alloc(wB); }
  size_t ybB = (size_t)PADMAX * DN * 2;
  size_t afterW = (off + 255) & ~(size_t)255;
  bool dense = ws_size >= afterW + ybB + (size_t)128 * HN * 2 + 4096;
  size_t ybO = 0;
  if (dense) ybO = alloc(ybB);
  size_t hbase = (off + 255) & ~(size_t)255;
  size_t avail = ws_size > hbase ? ws_size - hbase : (size_t)128 * HN * 2;
  long Cl = (long)(avail / ((size_t)HN * 2));
  if (Cl > PADMAX) Cl = PADMAX;
  Cl &= ~127l;
  if (Cl < 128) Cl = 128;
  int C = (int)Cl;
  size_t hbO = alloc((size_t)C * HN * 2);
  int nCh = (PADMAX + C - 1) / C;

  int* cnt = (int*)(W + ctrlO);
  int* cursor = cnt + 8;
  int* poff = cnt + 16;
  int* eids = (int*)(W + eidsO);
  float* wts = (float*)(W + wtsO);
  int* pairTok = (int*)(W + ptokO);
  float* pairW = (float*)(W + pwO);
  int* slotPos = (int*)(W + sposO);
  unsigned short* xg = (unsigned short*)(W + xgO);
  unsigned short* hb = (unsigned short*)(W + hbO);
  unsigned short* yb = (unsigned short*)(W + ybO);

  hipFuncSetAttribute(reinterpret_cast<const void*>(moe_gemm128_k<1, true>),
                      hipFuncAttributeMaxDynamicSharedMemorySize, 65536);
  hipFuncSetAttribute(reinterpret_cast<const void*>(moe_gemm128_k<2, true>),
                      hipFuncAttributeMaxDynamicSharedMemorySize, 65536);
  hipFuncSetAttribute(reinterpret_cast<const void*>(moe_gemm128_k<3, true>),
                      hipFuncAttributeMaxDynamicSharedMemorySize, 65536);
  hipFuncSetAttribute(reinterpret_cast<const void*>(moe_gemm128_k<1, false>),
                      hipFuncAttributeMaxDynamicSharedMemorySize, 65536);
  hipFuncSetAttribute(reinterpret_cast<const void*>(moe_gemm128_k<2, false>),
                      hipFuncAttributeMaxDynamicSharedMemorySize, 65536);
  hipFuncSetAttribute(reinterpret_cast<const void*>(moe_gemm128_k<3, false>),
                      hipFuncAttributeMaxDynamicSharedMemorySize, 65536);

  hipMemsetAsync(W + ctrlO, 0, 256, stream);
  hipMemsetAsync(W + ptokO, 0xFF, (size_t)PADMAX * 4, stream);  // pairTok = -1
  if (!dense) hipMemsetAsync(d_out, 0, (size_t)TN * DN * 4, stream);

  const int nCvtBlk = 4096;
  if (bw) {
    prep_k<<<TN / 4 + nCvtBlk, 256, 0, stream>>>(
        x, rw, w1, w2, (unsigned short*)(W + w1bO), (unsigned short*)(W + w2bO),
        eids, wts, cnt, nCvtBlk, (long)EN * HN * DN / 4);
  } else {
    prep_k<<<TN / 4, 256, 0, stream>>>(x, rw, w1, w2, nullptr, nullptr,
                                       eids, wts, cnt, 1, 0);
  }
  offsets_k<<<1, 1, 0, stream>>>(cnt, poff);
  scatter_k<<<TN / 256, 256, 0, stream>>>(eids, wts, poff, cursor, pairTok, pairW, slotPos);
  gather_k<<<PADMAX / 4, 256, 0, stream>>>(x, pairTok, xg);

  int Ctiles = C / 128;
  for (int c = 0; c < nCh; ++c) {
    int cs = c * C;
    if (bw) {
      moe_gemm128_k<1, true><<<dim3(HN / 128, Ctiles, 1), 256, 65536, stream>>>(
          xg, W + w1bO, hb, pairTok, pairW, poff, cs);
      if (dense) {
        moe_gemm128_k<2, true><<<dim3(DN / 128, Ctiles, 1), 256, 65536, stream>>>(
            hb, W + w2bO, yb, pairTok, pairW, poff, cs);
      } else {
        moe_gemm128_k<3, true><<<dim3(DN / 128, Ctiles, 2), 256, 65536, stream>>>(
            hb, W + w2bO, d_out, pairTok, pairW, poff, cs);
      }
    } else {
      moe_gemm128_k<1, false><<<dim3(HN / 128, Ctiles, 1), 256, 65536, stream>>>(
          xg, w1, hb, pairTok, pairW, poff, cs);
      if (dense) {
        moe_gemm128_k<2, false><<<dim3(DN / 128, Ctiles, 1), 256, 65536, stream>>>(
            hb, w2, yb, pairTok, pairW, poff, cs);
      } else {
        moe_gemm128_k<3, false><<<dim3(DN / 128, Ctiles, 2), 256, 65536, stream>>>(
            hb, w2, d_out, pairTok, pairW, poff, cs);
      }
    }
  }
  if (dense) {
    combine_k<<<TN, 256, 0, stream>>>(yb, wts, slotPos, (float*)d_out);
  }
}